// Round 1
// baseline (331.880 us; speedup 1.0000x reference)
//
#include <hip/hip_runtime.h>
#include <hip/hip_bf16.h>

using f32x4  = __attribute__((ext_vector_type(4))) float;
using bf16x8 = __attribute__((ext_vector_type(8))) __bf16;
using u16x8  = __attribute__((ext_vector_type(8))) unsigned short;

#define DEV __device__ __forceinline__

constexpr int S_  = 4096;
constexpr int D_  = 1024;
constexpr int H_  = 16;
constexpr int DH_ = 64;
constexpr int KD  = 1024;   // contraction dim for both GEMMs

// ---- ws layout (byte offsets) ----
constexpr size_t XB_OFF   = 0;                       // x bf16        [4096][1024]
constexpr size_t WQKV_OFF = 8388608;                 // Wqkv bf16     [3072][1024]
constexpr size_t WOUT_OFF = 14680064;                // out_w bf16    [1024][1024]
constexpr size_t QB_OFF   = 16777216;                // Q bf16        [16][4096][64]
constexpr size_t KB_OFF   = 25165824;                // K*scale bf16  [16][4096][64]
constexpr size_t VT_OFF   = 33554432;                // V^T bf16      [16][64][4096]
constexpr size_t CTX_OFF  = 41943040;                // ctx bf16      [4096][1024]

DEV unsigned short f2bf(float f) {
  __hip_bfloat16 h = __float2bfloat16(f);
  return __builtin_bit_cast(unsigned short, h);
}

DEV void gl_lds16(const void* g, void* l) {
  __builtin_amdgcn_global_load_lds(
      (const __attribute__((address_space(1))) void*)g,
      (__attribute__((address_space(3))) void*)l, 16, 0, 0);
}

DEV f32x4 mfma16(bf16x8 a, bf16x8 b, f32x4 c) {
  return __builtin_amdgcn_mfma_f32_16x16x32_bf16(a, b, c, 0, 0, 0);
}

// ---------------- f32 -> bf16 conversion, 8 elems/thread ----------------
__global__ void cvt_k(const float* __restrict__ s, unsigned short* __restrict__ d, int n8) {
  int i = blockIdx.x * 256 + threadIdx.x;
  if (i >= n8) return;
  const float4* s4 = (const float4*)s;
  float4 a = s4[2 * i], b = s4[2 * i + 1];
  u16x8 o;
  o[0] = f2bf(a.x); o[1] = f2bf(a.y); o[2] = f2bf(a.z); o[3] = f2bf(a.w);
  o[4] = f2bf(b.x); o[5] = f2bf(b.y); o[6] = f2bf(b.z); o[7] = f2bf(b.w);
  ((u16x8*)d)[i] = o;
}

// ---------------- GEMM C = A(MxK) * Bt(NxK)^T, 128x128 tile, BK=32 ----------------
// EPI 0: qkv epilogue (split q/k/v, k*0.125, v transposed), EPI 1: f32 out + bias
template <int EPI>
__global__ __launch_bounds__(256)
void gemm_bt_k(const unsigned short* __restrict__ A,
               const unsigned short* __restrict__ Bt,
               const float* __restrict__ bias,
               unsigned short* __restrict__ qb,
               unsigned short* __restrict__ kb,
               unsigned short* __restrict__ vt,
               float* __restrict__ outf) {
  __shared__ unsigned short As[128 * 32];
  __shared__ unsigned short Bs[128 * 32];
  const int t = threadIdx.x;
  const int w = t >> 6, l = t & 63;
  const int lr = l & 15, lg = l >> 4, lk = lg * 8;
  const int m0 = blockIdx.y * 128, n0 = blockIdx.x * 128;
  const int wm = (w >> 1) * 64, wn = (w & 1) * 64;

  f32x4 acc[4][4] = {};

  const int srow = t >> 2;            // 0..63 (row within half-tile)
  const int scolb = (t & 3) << 4;     // byte col 0/16/32/48
  const char* Ag = (const char*)A + (size_t)(m0 + srow) * (KD * 2) + scolb;
  const char* Bg = (const char*)Bt + (size_t)(n0 + srow) * (KD * 2) + scolb;
  char* AsB = (char*)As;
  char* BsB = (char*)Bs;

  for (int kt = 0; kt < KD / 32; ++kt) {
    const char* ak = Ag + kt * 64;
    const char* bk = Bg + kt * 64;
    gl_lds16(ak,                 AsB + t * 16);
    gl_lds16(ak + 64 * (KD * 2), AsB + 4096 + t * 16);
    gl_lds16(bk,                 BsB + t * 16);
    gl_lds16(bk + 64 * (KD * 2), BsB + 4096 + t * 16);
    __syncthreads();

    bf16x8 a[4], b[4];
#pragma unroll
    for (int mi = 0; mi < 4; ++mi)
      a[mi] = *(const bf16x8*)&As[(wm + mi * 16 + lr) * 32 + lk];
#pragma unroll
    for (int ni = 0; ni < 4; ++ni)
      b[ni] = *(const bf16x8*)&Bs[(wn + ni * 16 + lr) * 32 + lk];
#pragma unroll
    for (int mi = 0; mi < 4; ++mi)
#pragma unroll
      for (int ni = 0; ni < 4; ++ni)
        acc[mi][ni] = mfma16(a[mi], b[ni], acc[mi][ni]);
    __syncthreads();
  }

  const int r0 = lg * 4;
  if (EPI == 0) {
    const int which = n0 >> 10;  // 0=q 1=k 2=v (128-tile never straddles)
#pragma unroll
    for (int mi = 0; mi < 4; ++mi) {
      const int sbase = m0 + wm + mi * 16 + r0;
#pragma unroll
      for (int ni = 0; ni < 4; ++ni) {
        const int e = n0 + wn + ni * 16 + lr;
        const float bv = bias[e];
        const int h = (e & 1023) >> 6, dd = e & 63;
#pragma unroll
        for (int r = 0; r < 4; ++r) {
          const float v = acc[mi][ni][r] + bv;
          const int sr = sbase + r;
          if (which == 0)      qb[((size_t)(h * S_ + sr)) * 64 + dd] = f2bf(v);
          else if (which == 1) kb[((size_t)(h * S_ + sr)) * 64 + dd] = f2bf(v * 0.125f);
          else                 vt[((size_t)(h * 64 + dd)) * S_ + sr] = f2bf(v);
        }
      }
    }
  } else {
#pragma unroll
    for (int mi = 0; mi < 4; ++mi) {
      const int sbase = m0 + wm + mi * 16 + r0;
#pragma unroll
      for (int ni = 0; ni < 4; ++ni) {
        const int e = n0 + wn + ni * 16 + lr;
        const float bv = bias[e];
#pragma unroll
        for (int r = 0; r < 4; ++r)
          outf[(size_t)(sbase + r) * D_ + e] = acc[mi][ni][r] + bv;
      }
    }
  }
}

// ---------------- causal flash attention ----------------
// grid (64 qtiles, 16 heads), 256 thr = 4 waves, QBLK=64 (16 rows/wave), KVBLK=64
__global__ __launch_bounds__(256)
void attn_k(const unsigned short* __restrict__ Qb,
            const unsigned short* __restrict__ Kb,
            const unsigned short* __restrict__ Vt,
            unsigned short* __restrict__ ctx) {
  __shared__ unsigned short Ks[64 * 64];   // [kv][d]
  __shared__ unsigned short Vs[64 * 64];   // [d][kv]  (from V^T)
  __shared__ unsigned short Ps[4][16 * 64];// per-wave [m][kv]

  const int t = threadIdx.x, w = t >> 6, l = t & 63;
  const int lr = l & 15, lg = l >> 4, lk = lg * 8;
  const int qb = (gridDim.x - 1) - blockIdx.x;  // heavy blocks first
  const int h = blockIdx.y;
  const int q0 = qb * 64;

  // Q fragments (held in registers for whole kv loop)
  const unsigned short* Qrow = Qb + ((size_t)(h * S_ + q0 + w * 16 + lr)) * 64;
  bf16x8 qf0 = *(const bf16x8*)(Qrow + lk);
  bf16x8 qf1 = *(const bf16x8*)(Qrow + 32 + lk);

  f32x4 cacc[4] = {};
  float mrow[4], lrow[4];
#pragma unroll
  for (int r = 0; r < 4; ++r) { mrow[r] = -INFINITY; lrow[r] = 0.f; }

  const int myrow = q0 + w * 16 + lg * 4;

  for (int tkv = 0; tkv <= qb; ++tkv) {
    const int kv0 = tkv * 64;
    // stage K tile: contiguous 8KB
    const char* Kg = (const char*)(Kb + ((size_t)h * S_ + kv0) * 64) + t * 16;
    gl_lds16(Kg,        (char*)Ks + t * 16);
    gl_lds16(Kg + 4096, (char*)Ks + 4096 + t * 16);
    // stage V^T tile: rows d (stride S*2 B), 2 chunks of 32 rows
    const char* Vg = (const char*)Vt + ((size_t)(h * 64 + (t >> 3)) * S_ + kv0) * 2 + (t & 7) * 16;
    gl_lds16(Vg,                (char*)Vs + t * 16);
    gl_lds16(Vg + 32 * S_ * 2,  (char*)Vs + 4096 + t * 16);
    __syncthreads();

    // QK^T
    f32x4 sacc[4] = {};
#pragma unroll
    for (int nb = 0; nb < 4; ++nb) {
      bf16x8 k0 = *(const bf16x8*)&Ks[(nb * 16 + lr) * 64 + lk];
      bf16x8 k1 = *(const bf16x8*)&Ks[(nb * 16 + lr) * 64 + 32 + lk];
      sacc[nb] = mfma16(qf0, k0, sacc[nb]);
      sacc[nb] = mfma16(qf1, k1, sacc[nb]);
    }

    // causal mask (only diagonal tile)
    if (tkv == qb) {
#pragma unroll
      for (int nb = 0; nb < 4; ++nb)
#pragma unroll
        for (int r = 0; r < 4; ++r)
          if (kv0 + nb * 16 + lr > myrow + r) sacc[nb][r] = -INFINITY;
    }

    // online softmax (row r lives on 16 lanes sharing lg)
    float vm[4];
#pragma unroll
    for (int r = 0; r < 4; ++r)
      vm[r] = fmaxf(fmaxf(sacc[0][r], sacc[1][r]), fmaxf(sacc[2][r], sacc[3][r]));
#pragma unroll
    for (int msk = 1; msk < 16; msk <<= 1)
#pragma unroll
      for (int r = 0; r < 4; ++r) vm[r] = fmaxf(vm[r], __shfl_xor(vm[r], msk));

    float alpha[4];
#pragma unroll
    for (int r = 0; r < 4; ++r) {
      const float mnew = fmaxf(mrow[r], vm[r]);
      alpha[r] = __expf(mrow[r] - mnew);
      mrow[r] = mnew;
    }

    float rs[4] = {0.f, 0.f, 0.f, 0.f};
#pragma unroll
    for (int nb = 0; nb < 4; ++nb)
#pragma unroll
      for (int r = 0; r < 4; ++r) {
        const float p = __expf(sacc[nb][r] - mrow[r]);
        rs[r] += p;
        Ps[w][(lg * 4 + r) * 64 + nb * 16 + lr] = f2bf(p);
      }
#pragma unroll
    for (int msk = 1; msk < 16; msk <<= 1)
#pragma unroll
      for (int r = 0; r < 4; ++r) rs[r] += __shfl_xor(rs[r], msk);
#pragma unroll
    for (int r = 0; r < 4; ++r) lrow[r] = lrow[r] * alpha[r] + rs[r];

    // rescale running context
#pragma unroll
    for (int nb = 0; nb < 4; ++nb)
#pragma unroll
      for (int r = 0; r < 4; ++r) cacc[nb][r] *= alpha[r];

    __builtin_amdgcn_wave_barrier();

    // PV: A = P[m][kv] from LDS, B = V^T[d][kv]
    bf16x8 pf0 = *(const bf16x8*)&Ps[w][lr * 64 + lk];
    bf16x8 pf1 = *(const bf16x8*)&Ps[w][lr * 64 + 32 + lk];
#pragma unroll
    for (int db = 0; db < 4; ++db) {
      bf16x8 v0 = *(const bf16x8*)&Vs[(db * 16 + lr) * 64 + lk];
      bf16x8 v1 = *(const bf16x8*)&Vs[(db * 16 + lr) * 64 + 32 + lk];
      cacc[db] = mfma16(pf0, v0, cacc[db]);
      cacc[db] = mfma16(pf1, v1, cacc[db]);
    }
    __syncthreads();
  }

  // epilogue: ctx[s][h*64+d] bf16
#pragma unroll
  for (int r = 0; r < 4; ++r) {
    const float inv = 1.0f / lrow[r];
    const int sr = q0 + w * 16 + lg * 4 + r;
#pragma unroll
    for (int db = 0; db < 4; ++db)
      ctx[(size_t)sr * D_ + h * 64 + db * 16 + lr] = f2bf(cacc[db][r] * inv);
  }
}

extern "C" void kernel_launch(void* const* d_in, const int* in_sizes, int n_in,
                              void* d_out, int out_size, void* d_ws, size_t ws_size,
                              hipStream_t stream) {
  const float* x      = (const float*)d_in[0];
  const float* Wqkv_w = (const float*)d_in[1];
  const float* Wqkv_b = (const float*)d_in[2];
  const float* out_w  = (const float*)d_in[3];
  const float* out_b  = (const float*)d_in[4];
  float* out = (float*)d_out;
  char* ws = (char*)d_ws;

  unsigned short* xb    = (unsigned short*)(ws + XB_OFF);
  unsigned short* wqkvb = (unsigned short*)(ws + WQKV_OFF);
  unsigned short* woutb = (unsigned short*)(ws + WOUT_OFF);
  unsigned short* Qb    = (unsigned short*)(ws + QB_OFF);
  unsigned short* Kb    = (unsigned short*)(ws + KB_OFF);
  unsigned short* Vt    = (unsigned short*)(ws + VT_OFF);
  unsigned short* ctx   = (unsigned short*)(ws + CTX_OFF);

  // 1. convert inputs to bf16
  cvt_k<<<2048, 256, 0, stream>>>(x, xb, 4096 * 1024 / 8);
  cvt_k<<<1536, 256, 0, stream>>>(Wqkv_w, wqkvb, 3072 * 1024 / 8);
  cvt_k<<<512, 256, 0, stream>>>(out_w, woutb, 1024 * 1024 / 8);

  // 2. QKV GEMM + split/scale/transpose epilogue
  gemm_bt_k<0><<<dim3(24, 32), 256, 0, stream>>>(xb, wqkvb, Wqkv_b, Qb, Kb, Vt, nullptr);

  // 3. causal flash attention
  attn_k<<<dim3(64, 16), 256, 0, stream>>>(Qb, Kb, Vt, ctx);

  // 4. output projection (f32 out + bias)
  gemm_bt_k<1><<<dim3(8, 32), 256, 0, stream>>>(ctx, woutb, out_b, nullptr, nullptr, nullptr, out);
}

// Round 3
// 268.417 us; speedup vs baseline: 1.2364x; 1.2364x over previous
//
#include <hip/hip_runtime.h>
#include <hip/hip_bf16.h>

using f32x4  = __attribute__((ext_vector_type(4))) float;
using bf16x8 = __attribute__((ext_vector_type(8))) __bf16;
using u16x8  = __attribute__((ext_vector_type(8))) unsigned short;

#define DEV __device__ __forceinline__

constexpr int S_  = 4096;
constexpr int D_  = 1024;
constexpr int H_  = 16;
constexpr int DH_ = 64;
constexpr int KD  = 1024;   // contraction dim for both GEMMs

// ---- ws layout (byte offsets) ----
constexpr size_t XB_OFF   = 0;                       // x bf16        [4096][1024]
constexpr size_t WQKV_OFF = 8388608;                 // Wqkv bf16     [3072][1024]
constexpr size_t WOUT_OFF = 14680064;                // out_w bf16    [1024][1024]
constexpr size_t QB_OFF   = 16777216;                // Q bf16        [16][4096][64]
constexpr size_t KB_OFF   = 25165824;                // K*scale bf16  [16][4096][64]
constexpr size_t VT_OFF   = 33554432;                // V^T bf16      [16][64][4096]
constexpr size_t CTX_OFF  = 41943040;                // ctx bf16      [4096][1024]

DEV unsigned short f2bf(float f) {
  __hip_bfloat16 h = __float2bfloat16(f);
  return __builtin_bit_cast(unsigned short, h);
}

DEV void gl_lds16(const void* g, void* l) {
  __builtin_amdgcn_global_load_lds(
      (const __attribute__((address_space(1))) void*)g,
      (__attribute__((address_space(3))) void*)l, 16, 0, 0);
}

DEV f32x4 mfma16(bf16x8 a, bf16x8 b, f32x4 c) {
  return __builtin_amdgcn_mfma_f32_16x16x32_bf16(a, b, c, 0, 0, 0);
}

// ---------------- f32 -> bf16 conversion, 8 elems/thread ----------------
__global__ void cvt_k(const float* __restrict__ s, unsigned short* __restrict__ d, int n8) {
  int i = blockIdx.x * 256 + threadIdx.x;
  if (i >= n8) return;
  const float4* s4 = (const float4*)s;
  float4 a = s4[2 * i], b = s4[2 * i + 1];
  u16x8 o;
  o[0] = f2bf(a.x); o[1] = f2bf(a.y); o[2] = f2bf(a.z); o[3] = f2bf(a.w);
  o[4] = f2bf(b.x); o[5] = f2bf(b.y); o[6] = f2bf(b.z); o[7] = f2bf(b.w);
  ((u16x8*)d)[i] = o;
}

// ---------------- GEMM C = A(MxK) * Bt(NxK)^T, 128x128 tile, BK=32 ----------------
// EPI 0: qkv epilogue (split q/k/v, k*0.125, v transposed), EPI 1: f32 out + bias
template <int EPI>
__global__ __launch_bounds__(256)
void gemm_bt_k(const unsigned short* __restrict__ A,
               const unsigned short* __restrict__ Bt,
               const float* __restrict__ bias,
               unsigned short* __restrict__ qb,
               unsigned short* __restrict__ kb,
               unsigned short* __restrict__ vt,
               float* __restrict__ outf) {
  __shared__ unsigned short As[128 * 32];
  __shared__ unsigned short Bs[128 * 32];
  const int t = threadIdx.x;
  const int w = t >> 6, l = t & 63;
  const int lr = l & 15, lg = l >> 4, lk = lg * 8;
  const int m0 = blockIdx.y * 128, n0 = blockIdx.x * 128;
  const int wm = (w >> 1) * 64, wn = (w & 1) * 64;

  f32x4 acc[4][4] = {};

  const int srow = t >> 2;            // 0..63 (row within half-tile)
  const int scolb = (t & 3) << 4;     // byte col 0/16/32/48
  const char* Ag = (const char*)A + (size_t)(m0 + srow) * (KD * 2) + scolb;
  const char* Bg = (const char*)Bt + (size_t)(n0 + srow) * (KD * 2) + scolb;
  char* AsB = (char*)As;
  char* BsB = (char*)Bs;

  for (int kt = 0; kt < KD / 32; ++kt) {
    const char* ak = Ag + kt * 64;
    const char* bk = Bg + kt * 64;
    gl_lds16(ak,                 AsB + t * 16);
    gl_lds16(ak + 64 * (KD * 2), AsB + 4096 + t * 16);
    gl_lds16(bk,                 BsB + t * 16);
    gl_lds16(bk + 64 * (KD * 2), BsB + 4096 + t * 16);
    __syncthreads();

    bf16x8 a[4], b[4];
#pragma unroll
    for (int mi = 0; mi < 4; ++mi)
      a[mi] = *(const bf16x8*)&As[(wm + mi * 16 + lr) * 32 + lk];
#pragma unroll
    for (int ni = 0; ni < 4; ++ni)
      b[ni] = *(const bf16x8*)&Bs[(wn + ni * 16 + lr) * 32 + lk];
#pragma unroll
    for (int mi = 0; mi < 4; ++mi)
#pragma unroll
      for (int ni = 0; ni < 4; ++ni)
        acc[mi][ni] = mfma16(a[mi], b[ni], acc[mi][ni]);
    __syncthreads();
  }

  const int r0 = lg * 4;
  if (EPI == 0) {
    const int which = n0 >> 10;  // 0=q 1=k 2=v (128-tile never straddles)
#pragma unroll
    for (int mi = 0; mi < 4; ++mi) {
      const int sbase = m0 + wm + mi * 16 + r0;
#pragma unroll
      for (int ni = 0; ni < 4; ++ni) {
        const int e = n0 + wn + ni * 16 + lr;
        const float bv = bias[e];
        const int h = (e & 1023) >> 6, dd = e & 63;
#pragma unroll
        for (int r = 0; r < 4; ++r) {
          const float v = acc[mi][ni][r] + bv;
          const int sr = sbase + r;
          if (which == 0)      qb[((size_t)(h * S_ + sr)) * 64 + dd] = f2bf(v);
          else if (which == 1) kb[((size_t)(h * S_ + sr)) * 64 + dd] = f2bf(v * 0.125f);
          else                 vt[((size_t)(h * 64 + dd)) * S_ + sr] = f2bf(v);
        }
      }
    }
  } else {
#pragma unroll
    for (int mi = 0; mi < 4; ++mi) {
      const int sbase = m0 + wm + mi * 16 + r0;
#pragma unroll
      for (int ni = 0; ni < 4; ++ni) {
        const int e = n0 + wn + ni * 16 + lr;
        const float bv = bias[e];
#pragma unroll
        for (int r = 0; r < 4; ++r)
          outf[(size_t)(sbase + r) * D_ + e] = acc[mi][ni][r] + bv;
      }
    }
  }
}

// ---------------- causal flash attention ----------------
// grid (64 qtiles, 16 heads), 256 thr = 4 waves, QBLK=64 (16 rows/wave), KVBLK=64
// K/V LDS tiles XOR-swizzled (T2, both-sides: pre-swizzled global src + swizzled read)
// P tile padded to stride 72 elem. K/V double-buffered, prefetch under compute.
__global__ __launch_bounds__(256)
void attn_k(const unsigned short* __restrict__ Qb,
            const unsigned short* __restrict__ Kb,
            const unsigned short* __restrict__ Vt,
            unsigned short* __restrict__ ctx) {
  __shared__ unsigned short Ks[2][64 * 64];   // [kv][d] swizzled
  __shared__ unsigned short Vs[2][64 * 64];   // [d][kv] swizzled (from V^T)
  __shared__ unsigned short Ps[4][16 * 72];   // per-wave [m][kv], padded stride 72

  const int t = threadIdx.x, w = t >> 6, l = t & 63;
  const int lr = l & 15, lg = l >> 4, lk = lg * 8;
  const int qb = (gridDim.x - 1) - blockIdx.x;  // heavy blocks first
  const int h = blockIdx.y;
  const int q0 = qb * 64;

  // staging addresses: thread t fills LDS bytes [t*16, t*16+16) of each 4KB half.
  // linear LDS row = srow (+32), within-row byte = (t&7)*16; source column is
  // inverse-swizzled (XOR is an involution).
  const int srow = t >> 3;                                  // 0..31
  const int ssw  = ((t & 7) << 4) ^ ((srow & 7) << 4);      // swizzled src col byte
  const char* Kg0 = (const char*)Kb + (size_t)(h * S_) * 128;
  const char* Vg0 = (const char*)Vt + (size_t)(h * 64) * (size_t)(S_ * 2);

  // per-lane swizzled column offsets for ds_read_b128 (row&7 == lr&7 always)
  // fragment 0 = row bytes [lg*16, +16), fragment 1 = row bytes [64+lg*16, +16)
  const int swz = (lr & 7) << 4;
  const int cA = (lg * 16) ^ swz;
  const int cB = (64 + lg * 16) ^ swz;

  // Q fragments (held in registers for whole kv loop)
  const unsigned short* Qrow = Qb + ((size_t)(h * S_ + q0 + w * 16 + lr)) * 64;
  bf16x8 qf0 = *(const bf16x8*)(Qrow + lk);
  bf16x8 qf1 = *(const bf16x8*)(Qrow + 32 + lk);

  f32x4 cacc[4] = {};
  float mrow[4], lrow[4];
#pragma unroll
  for (int r = 0; r < 4; ++r) { mrow[r] = -INFINITY; lrow[r] = 0.f; }

  const int myrow = q0 + w * 16 + lg * 4;

  auto stage = [&](int b, int kv0) {
    const char* Kg = Kg0 + (size_t)kv0 * 128;
    char* kd = (char*)&Ks[b][0];
    gl_lds16(Kg + (size_t)srow * 128 + ssw,        kd + t * 16);
    gl_lds16(Kg + (size_t)(32 + srow) * 128 + ssw, kd + 4096 + t * 16);
    const char* Vg = Vg0 + (size_t)kv0 * 2;
    char* vd = (char*)&Vs[b][0];
    gl_lds16(Vg + (size_t)srow * (S_ * 2) + ssw,        vd + t * 16);
    gl_lds16(Vg + (size_t)(32 + srow) * (S_ * 2) + ssw, vd + 4096 + t * 16);
  };

  stage(0, 0);
  int cur = 0;

  for (int tkv = 0; tkv <= qb; ++tkv) {
    __syncthreads();                      // drains staged loads for buf `cur`
    if (tkv < qb) stage(cur ^ 1, (tkv + 1) * 64);   // prefetch under compute
    const int kv0 = tkv * 64;

    // QK^T
    f32x4 sacc[4] = {};
    const char* ksb = (const char*)&Ks[cur][0] + lr * 128;
#pragma unroll
    for (int nb = 0; nb < 4; ++nb) {
      const char* kr = ksb + nb * (16 * 128);
      bf16x8 k0 = *(const bf16x8*)(kr + cA);
      bf16x8 k1 = *(const bf16x8*)(kr + cB);
      sacc[nb] = mfma16(qf0, k0, sacc[nb]);
      sacc[nb] = mfma16(qf1, k1, sacc[nb]);
    }

    // causal mask (only diagonal tile)
    if (tkv == qb) {
#pragma unroll
      for (int nb = 0; nb < 4; ++nb)
#pragma unroll
        for (int r = 0; r < 4; ++r)
          if (kv0 + nb * 16 + lr > myrow + r) sacc[nb][r] = -INFINITY;
    }

    // online softmax (row r lives on 16 lanes sharing lg)
    float vm[4];
#pragma unroll
    for (int r = 0; r < 4; ++r)
      vm[r] = fmaxf(fmaxf(sacc[0][r], sacc[1][r]), fmaxf(sacc[2][r], sacc[3][r]));
#pragma unroll
    for (int msk = 1; msk < 16; msk <<= 1)
#pragma unroll
      for (int r = 0; r < 4; ++r) vm[r] = fmaxf(vm[r], __shfl_xor(vm[r], msk));

    float alpha[4];
#pragma unroll
    for (int r = 0; r < 4; ++r) {
      const float mnew = fmaxf(mrow[r], vm[r]);
      alpha[r] = __expf(mrow[r] - mnew);
      mrow[r] = mnew;
    }

    float rs[4] = {0.f, 0.f, 0.f, 0.f};
#pragma unroll
    for (int nb = 0; nb < 4; ++nb)
#pragma unroll
      for (int r = 0; r < 4; ++r) {
        const float p = __expf(sacc[nb][r] - mrow[r]);
        rs[r] += p;
        Ps[w][(lg * 4 + r) * 72 + nb * 16 + lr] = f2bf(p);
      }
#pragma unroll
    for (int msk = 1; msk < 16; msk <<= 1)
#pragma unroll
      for (int r = 0; r < 4; ++r) rs[r] += __shfl_xor(rs[r], msk);
#pragma unroll
    for (int r = 0; r < 4; ++r) lrow[r] = lrow[r] * alpha[r] + rs[r];

    // rescale running context
#pragma unroll
    for (int nb = 0; nb < 4; ++nb)
#pragma unroll
      for (int r = 0; r < 4; ++r) cacc[nb][r] *= alpha[r];

    __builtin_amdgcn_wave_barrier();

    // PV: A = P[m][kv] from padded LDS, B = V^T[d][kv] swizzled
    bf16x8 pf0 = *(const bf16x8*)&Ps[w][lr * 72 + lk];
    bf16x8 pf1 = *(const bf16x8*)&Ps[w][lr * 72 + lk + 32];
    const char* vsb = (const char*)&Vs[cur][0] + lr * 128;
#pragma unroll
    for (int db = 0; db < 4; ++db) {
      const char* vr = vsb + db * (16 * 128);
      bf16x8 v0 = *(const bf16x8*)(vr + cA);
      bf16x8 v1 = *(const bf16x8*)(vr + cB);
      cacc[db] = mfma16(pf0, v0, cacc[db]);
      cacc[db] = mfma16(pf1, v1, cacc[db]);
    }
    cur ^= 1;
  }

  // epilogue: ctx[s][h*64+d] bf16
#pragma unroll
  for (int r = 0; r < 4; ++r) {
    const float inv = 1.0f / lrow[r];
    const int sr = q0 + w * 16 + lg * 4 + r;
#pragma unroll
    for (int db = 0; db < 4; ++db)
      ctx[(size_t)sr * D_ + h * 64 + db * 16 + lr] = f2bf(cacc[db][r] * inv);
  }
}

extern "C" void kernel_launch(void* const* d_in, const int* in_sizes, int n_in,
                              void* d_out, int out_size, void* d_ws, size_t ws_size,
                              hipStream_t stream) {
  const float* x      = (const float*)d_in[0];
  const float* Wqkv_w = (const float*)d_in[1];
  const float* Wqkv_b = (const float*)d_in[2];
  const float* out_w  = (const float*)d_in[3];
  const float* out_b  = (const float*)d_in[4];
  float* out = (float*)d_out;
  char* ws = (char*)d_ws;

  unsigned short* xb    = (unsigned short*)(ws + XB_OFF);
  unsigned short* wqkvb = (unsigned short*)(ws + WQKV_OFF);
  unsigned short* woutb = (unsigned short*)(ws + WOUT_OFF);
  unsigned short* Qb    = (unsigned short*)(ws + QB_OFF);
  unsigned short* Kb    = (unsigned short*)(ws + KB_OFF);
  unsigned short* Vt    = (unsigned short*)(ws + VT_OFF);
  unsigned short* ctx   = (unsigned short*)(ws + CTX_OFF);

  // 1. convert inputs to bf16
  cvt_k<<<2048, 256, 0, stream>>>(x, xb, 4096 * 1024 / 8);
  cvt_k<<<1536, 256, 0, stream>>>(Wqkv_w, wqkvb, 3072 * 1024 / 8);
  cvt_k<<<512, 256, 0, stream>>>(out_w, woutb, 1024 * 1024 / 8);

  // 2. QKV GEMM + split/scale/transpose epilogue
  gemm_bt_k<0><<<dim3(24, 32), 256, 0, stream>>>(xb, wqkvb, Wqkv_b, Qb, Kb, Vt, nullptr);

  // 3. causal flash attention
  attn_k<<<dim3(64, 16), 256, 0, stream>>>(Qb, Kb, Vt, ctx);

  // 4. output projection (f32 out + bias)
  gemm_bt_k<1><<<dim3(8, 32), 256, 0, stream>>>(ctx, woutb, out_b, nullptr, nullptr, nullptr, out);
}

// Round 5
// 206.433 us; speedup vs baseline: 1.6077x; 1.3003x over previous
//
#include <hip/hip_runtime.h>
#include <hip/hip_bf16.h>

using f32x4  = __attribute__((ext_vector_type(4))) float;
using f32x16 = __attribute__((ext_vector_type(16))) float;
using bf16x8 = __attribute__((ext_vector_type(8))) __bf16;
using u16x8  = __attribute__((ext_vector_type(8))) unsigned short;
using u32x4  = __attribute__((ext_vector_type(4))) unsigned int;

#define DEV __device__ __forceinline__

constexpr int S_  = 4096;
constexpr int D_  = 1024;
constexpr int KD  = 1024;   // contraction dim for both GEMMs

// ---- ws layout (byte offsets) ----
constexpr size_t XB_OFF   = 0;                       // x bf16        [4096][1024]
constexpr size_t WQKV_OFF = 8388608;                 // Wqkv bf16     [3072][1024]
constexpr size_t WOUT_OFF = 14680064;                // out_w bf16    [1024][1024]
constexpr size_t QB_OFF   = 16777216;                // Q bf16        [16][4096][64]
constexpr size_t KB_OFF   = 25165824;                // K*scale bf16  [16][4096][64]
constexpr size_t VT_OFF   = 33554432;                // V^T bf16      [16][64][4096]
constexpr size_t CTX_OFF  = 41943040;                // ctx bf16      [4096][1024]

DEV unsigned short f2bf(float f) {
  __hip_bfloat16 h = __float2bfloat16(f);
  return __builtin_bit_cast(unsigned short, h);
}

DEV void gl_lds16(const void* g, void* l) {
  __builtin_amdgcn_global_load_lds(
      (const __attribute__((address_space(1))) void*)g,
      (__attribute__((address_space(3))) void*)l, 16, 0, 0);
}

DEV f32x4 mfma16(bf16x8 a, bf16x8 b, f32x4 c) {
  return __builtin_amdgcn_mfma_f32_16x16x32_bf16(a, b, c, 0, 0, 0);
}
DEV f32x16 mfma32(bf16x8 a, bf16x8 b, f32x16 c) {
  return __builtin_amdgcn_mfma_f32_32x32x16_bf16(a, b, c, 0, 0, 0);
}
DEV unsigned cvtpk(float lo, float hi) {
  unsigned r;
  asm("v_cvt_pk_bf16_f32 %0, %1, %2" : "=v"(r) : "v"(lo), "v"(hi));
  return r;
}

// ---------------- f32 -> bf16 conversion, 8 elems/thread ----------------
__global__ void cvt_k(const float* __restrict__ s, unsigned short* __restrict__ d, int n8) {
  int i = blockIdx.x * 256 + threadIdx.x;
  if (i >= n8) return;
  const float4* s4 = (const float4*)s;
  float4 a = s4[2 * i], b = s4[2 * i + 1];
  u16x8 o;
  o[0] = f2bf(a.x); o[1] = f2bf(a.y); o[2] = f2bf(a.z); o[3] = f2bf(a.w);
  o[4] = f2bf(b.x); o[5] = f2bf(b.y); o[6] = f2bf(b.z); o[7] = f2bf(b.w);
  ((u16x8*)d)[i] = o;
}

// ---------------- GEMM C = A(MxK) * Bt(NxK)^T, 128x128 tile, BK=32 ----------------
template <int EPI>
__global__ __launch_bounds__(256)
void gemm_bt_k(const unsigned short* __restrict__ A,
               const unsigned short* __restrict__ Bt,
               const float* __restrict__ bias,
               unsigned short* __restrict__ qb,
               unsigned short* __restrict__ kb,
               unsigned short* __restrict__ vt,
               float* __restrict__ outf) {
  __shared__ unsigned short As[128 * 32];
  __shared__ unsigned short Bs[128 * 32];
  const int t = threadIdx.x;
  const int w = t >> 6, l = t & 63;
  const int lr = l & 15, lg = l >> 4, lk = lg * 8;
  const int m0 = blockIdx.y * 128, n0 = blockIdx.x * 128;
  const int wm = (w >> 1) * 64, wn = (w & 1) * 64;

  f32x4 acc[4][4] = {};

  const int srow = t >> 2;
  const int scolb = (t & 3) << 4;
  const char* Ag = (const char*)A + (size_t)(m0 + srow) * (KD * 2) + scolb;
  const char* Bg = (const char*)Bt + (size_t)(n0 + srow) * (KD * 2) + scolb;
  char* AsB = (char*)As;
  char* BsB = (char*)Bs;

  for (int kt = 0; kt < KD / 32; ++kt) {
    const char* ak = Ag + kt * 64;
    const char* bk = Bg + kt * 64;
    gl_lds16(ak,                 AsB + t * 16);
    gl_lds16(ak + 64 * (KD * 2), AsB + 4096 + t * 16);
    gl_lds16(bk,                 BsB + t * 16);
    gl_lds16(bk + 64 * (KD * 2), BsB + 4096 + t * 16);
    __syncthreads();

    bf16x8 a[4], b[4];
#pragma unroll
    for (int mi = 0; mi < 4; ++mi)
      a[mi] = *(const bf16x8*)&As[(wm + mi * 16 + lr) * 32 + lk];
#pragma unroll
    for (int ni = 0; ni < 4; ++ni)
      b[ni] = *(const bf16x8*)&Bs[(wn + ni * 16 + lr) * 32 + lk];
#pragma unroll
    for (int mi = 0; mi < 4; ++mi)
#pragma unroll
      for (int ni = 0; ni < 4; ++ni)
        acc[mi][ni] = mfma16(a[mi], b[ni], acc[mi][ni]);
    __syncthreads();
  }

  const int r0 = lg * 4;
  if (EPI == 0) {
    const int which = n0 >> 10;
#pragma unroll
    for (int mi = 0; mi < 4; ++mi) {
      const int sbase = m0 + wm + mi * 16 + r0;
#pragma unroll
      for (int ni = 0; ni < 4; ++ni) {
        const int e = n0 + wn + ni * 16 + lr;
        const float bv = bias[e];
        const int h = (e & 1023) >> 6, dd = e & 63;
#pragma unroll
        for (int r = 0; r < 4; ++r) {
          const float v = acc[mi][ni][r] + bv;
          const int sr = sbase + r;
          if (which == 0)      qb[((size_t)(h * S_ + sr)) * 64 + dd] = f2bf(v);
          else if (which == 1) kb[((size_t)(h * S_ + sr)) * 64 + dd] = f2bf(v * 0.125f);
          else                 vt[((size_t)(h * 64 + dd)) * S_ + sr] = f2bf(v);
        }
      }
    }
  } else {
#pragma unroll
    for (int mi = 0; mi < 4; ++mi) {
      const int sbase = m0 + wm + mi * 16 + r0;
#pragma unroll
      for (int ni = 0; ni < 4; ++ni) {
        const int e = n0 + wn + ni * 16 + lr;
        const float bv = bias[e];
#pragma unroll
        for (int r = 0; r < 4; ++r)
          outf[(size_t)(sbase + r) * D_ + e] = acc[mi][ni][r] + bv;
      }
    }
  }
}

// ---------------- causal flash attention, swapped-QK^T 32x32 ----------------
// grid (32 qtiles, 16 heads), 4 waves, wave owns 32 q-rows. KVBLK=64 staged
// (two 32-kv sub-tiles per barrier). S^T = K*Q^T so each lane owns one q-row:
// in-lane softmax; cross-half combine + P redistribution via __shfl_xor(32).
__global__ __launch_bounds__(256, 4)
void attn_k(const unsigned short* __restrict__ Qb,
            const unsigned short* __restrict__ Kb,
            const unsigned short* __restrict__ Vt,
            unsigned short* __restrict__ ctx) {
  __shared__ unsigned short Ks[2][64 * 64];   // [kv][d] swizzled
  __shared__ unsigned short Vs[2][64 * 64];   // [d][kv] swizzled (from V^T)

  const int t = threadIdx.x, w = t >> 6, l = t & 63;
  const int lq = l & 31, hi = l >> 5;
  const int bi = (gridDim.x - 1) - blockIdx.x;   // heavy blocks first
  const int h = blockIdx.y;
  const int q0 = bi * 128;
  const int qrow = q0 + w * 32 + lq;
  const int qwmin = q0 + w * 32, qwmax = qwmin + 31;

  const int srow = t >> 3;
  const int ssw  = ((t & 7) << 4) ^ ((srow & 7) << 4);
  const char* Kg0 = (const char*)Kb + (size_t)(h * S_) * 128;
  const char* Vg0 = (const char*)Vt + (size_t)(h * 64) * (size_t)(S_ * 2);

  // Q fragments: B-operand of S^T mfma: lane holds Q[q=lq][d0*16 + hi*8 + e]
  const unsigned short* Qr = Qb + ((size_t)(h * S_ + qrow)) * 64;
  bf16x8 qf[4];
#pragma unroll
  for (int d0 = 0; d0 < 4; ++d0)
    qf[d0] = *(const bf16x8*)(Qr + d0 * 16 + hi * 8);

  f32x16 cacc[2] = {};      // ctx^T[d][q], d-blocks 0..31 / 32..63
  float m = -INFINITY, lsum = 0.f;

  auto stage = [&](int b, int kv0) {
    char* kd = (char*)&Ks[b][0];
    const char* Kg = Kg0 + (size_t)kv0 * 128;
    gl_lds16(Kg + (size_t)srow * 128 + ssw,        kd + t * 16);
    gl_lds16(Kg + (size_t)(32 + srow) * 128 + ssw, kd + 4096 + t * 16);
    char* vd = (char*)&Vs[b][0];
    const char* Vg = Vg0 + (size_t)kv0 * 2;
    gl_lds16(Vg + (size_t)srow * (S_ * 2) + ssw,        vd + t * 16);
    gl_lds16(Vg + (size_t)(32 + srow) * (S_ * 2) + ssw, vd + 4096 + t * 16);
  };

  const int nt = 2 * (bi + 1);
  int cur = 0;
  stage(0, 0);

  for (int tt = 0; tt < nt; ++tt) {
    __syncthreads();
    if (tt + 1 < nt) stage(cur ^ 1, (tt + 1) * 64);
    const char* Kt = (const char*)&Ks[cur][0];
    const char* Vl = (const char*)&Vs[cur][0];

#pragma unroll
    for (int kvh = 0; kvh < 2; ++kvh) {
      const int kv0s = tt * 64 + kvh * 32;
      if (kv0s > qwmax) continue;     // wave-uniform: fully masked sub-tile

      // ---- S^T = K * Q^T : lane holds S^T[kv(r,hi)][q=lq] ----
      f32x16 st = {};
      const int kr = kvh * 32 + lq;
      const char* kbase = Kt + kr * 128;
      const int ksw = (kr & 7) << 4;
#pragma unroll
      for (int d0 = 0; d0 < 4; ++d0) {
        bf16x8 kf = *(const bf16x8*)(kbase + ((d0 * 32 + hi * 16) ^ ksw));
        st = mfma32(kf, qf[d0], st);
      }

      // ---- causal mask (diag-straddling sub-tiles only) ----
      if (kv0s + 31 > qwmin) {
#pragma unroll
        for (int r = 0; r < 16; ++r) {
          const int kvg = kv0s + (r & 3) + 8 * (r >> 2) + 4 * hi;
          if (kvg > qrow) st[r] = -INFINITY;
        }
      }

      // ---- in-lane online softmax (lane owns q-row; partner = lane^32) ----
      float pmax = st[0];
#pragma unroll
      for (int r = 1; r < 16; ++r) pmax = fmaxf(pmax, st[r]);
      pmax = fmaxf(pmax, __shfl_xor(pmax, 32));
      const float mnew = fmaxf(m, pmax);
      const float alpha = __expf(m - mnew);
      float p[16];
      float rs = 0.f;
#pragma unroll
      for (int r = 0; r < 16; ++r) { p[r] = __expf(st[r] - mnew); rs += p[r]; }
      rs += __shfl_xor(rs, 32);
      lsum = lsum * alpha + rs;
      m = mnew;
#pragma unroll
      for (int j = 0; j < 16; ++j) { cacc[0][j] *= alpha; cacc[1][j] *= alpha; }

      // ---- P^T B-frags: cvt_pk pairs + shfl_xor(32) + hi-select ----
      // lane owns P^T[kv=(r&3)+8*(r>>2)+4*hi][q=lq]; B-frag needs kv=hi*8+e.
      bf16x8 pf0, pf1;
      {
        unsigned x0 = cvtpk(p[0], p[1]), x1 = cvtpk(p[2], p[3]);
        unsigned y0 = cvtpk(p[4], p[5]), y1 = cvtpk(p[6], p[7]);
        unsigned px0 = __shfl_xor(x0, 32), px1 = __shfl_xor(x1, 32);
        unsigned py0 = __shfl_xor(y0, 32), py1 = __shfl_xor(y1, 32);
        u32x4 f0 = {hi ? py0 : x0, hi ? py1 : x1, hi ? y0 : px0, hi ? y1 : px1};
        pf0 = __builtin_bit_cast(bf16x8, f0);
      }
      {
        unsigned x0 = cvtpk(p[8], p[9]),  x1 = cvtpk(p[10], p[11]);
        unsigned y0 = cvtpk(p[12], p[13]), y1 = cvtpk(p[14], p[15]);
        unsigned px0 = __shfl_xor(x0, 32), px1 = __shfl_xor(x1, 32);
        unsigned py0 = __shfl_xor(y0, 32), py1 = __shfl_xor(y1, 32);
        u32x4 f1 = {hi ? py0 : x0, hi ? py1 : x1, hi ? y0 : px0, hi ? y1 : px1};
        pf1 = __builtin_bit_cast(bf16x8, f1);
      }

      // ---- PV: ctx^T[d][q] += V^T * P^T ----
#pragma unroll
      for (int db = 0; db < 2; ++db) {
        const int dr = db * 32 + lq;
        const char* vbase = Vl + dr * 128;
        const int vsw = (dr & 7) << 4;
        bf16x8 v0 = *(const bf16x8*)(vbase + ((kvh * 64 + hi * 16) ^ vsw));
        bf16x8 v1 = *(const bf16x8*)(vbase + ((kvh * 64 + 32 + hi * 16) ^ vsw));
        cacc[db] = mfma32(v0, pf0, cacc[db]);
        cacc[db] = mfma32(v1, pf1, cacc[db]);
      }
    }
    cur ^= 1;
  }

  // ---- epilogue: ctx[q][h*64+d], d = (r&3)+8*(r>>2)+4*hi+32*db ----
  const float inv = 1.0f / lsum;
  unsigned short* base = ctx + (size_t)qrow * D_ + h * 64;
#pragma unroll
  for (int db = 0; db < 2; ++db)
#pragma unroll
    for (int r = 0; r < 16; r += 2) {
      const unsigned wv = cvtpk(cacc[db][r] * inv, cacc[db][r + 1] * inv);
      const int d = (r & 3) + 8 * (r >> 2) + 4 * hi + 32 * db;
      *(unsigned*)(base + d) = wv;
    }
}

extern "C" void kernel_launch(void* const* d_in, const int* in_sizes, int n_in,
                              void* d_out, int out_size, void* d_ws, size_t ws_size,
                              hipStream_t stream) {
  const float* x      = (const float*)d_in[0];
  const float* Wqkv_w = (const float*)d_in[1];
  const float* Wqkv_b = (const float*)d_in[2];
  const float* out_w  = (const float*)d_in[3];
  const float* out_b  = (const float*)d_in[4];
  float* out = (float*)d_out;
  char* ws = (char*)d_ws;

  unsigned short* xb    = (unsigned short*)(ws + XB_OFF);
  unsigned short* wqkvb = (unsigned short*)(ws + WQKV_OFF);
  unsigned short* woutb = (unsigned short*)(ws + WOUT_OFF);
  unsigned short* Qb    = (unsigned short*)(ws + QB_OFF);
  unsigned short* Kb    = (unsigned short*)(ws + KB_OFF);
  unsigned short* Vt    = (unsigned short*)(ws + VT_OFF);
  unsigned short* ctx   = (unsigned short*)(ws + CTX_OFF);

  cvt_k<<<2048, 256, 0, stream>>>(x, xb, 4096 * 1024 / 8);
  cvt_k<<<1536, 256, 0, stream>>>(Wqkv_w, wqkvb, 3072 * 1024 / 8);
  cvt_k<<<512, 256, 0, stream>>>(out_w, woutb, 1024 * 1024 / 8);

  gemm_bt_k<0><<<dim3(24, 32), 256, 0, stream>>>(xb, wqkvb, Wqkv_b, Qb, Kb, Vt, nullptr);

  attn_k<<<dim3(32, 16), 256, 0, stream>>>(Qb, Kb, Vt, ctx);

  gemm_bt_k<1><<<dim3(8, 32), 256, 0, stream>>>(ctx, woutb, out_b, nullptr, nullptr, nullptr, out);
}

// Round 6
// 183.712 us; speedup vs baseline: 1.8065x; 1.1237x over previous
//
#include <hip/hip_runtime.h>
#include <hip/hip_bf16.h>

using f32x4  = __attribute__((ext_vector_type(4))) float;
using f32x16 = __attribute__((ext_vector_type(16))) float;
using bf16x8 = __attribute__((ext_vector_type(8))) __bf16;
using u16x8  = __attribute__((ext_vector_type(8))) unsigned short;
using u32x4  = __attribute__((ext_vector_type(4))) unsigned int;

#define DEV __device__ __forceinline__

constexpr int S_  = 4096;
constexpr int D_  = 1024;
constexpr int KD  = 1024;   // contraction dim for both GEMMs

// ---- ws layout (byte offsets) ----
constexpr size_t XB_OFF   = 0;                       // x bf16        [4096][1024]
constexpr size_t WQKV_OFF = 8388608;                 // Wqkv bf16     [3072][1024]
constexpr size_t WOUT_OFF = 14680064;                // out_w bf16    [1024][1024]
constexpr size_t QB_OFF   = 16777216;                // Q bf16        [16][4096][64]
constexpr size_t KB_OFF   = 25165824;                // K*scale bf16  [16][4096][64]
constexpr size_t VT_OFF   = 33554432;                // V^T bf16      [16][64][4096]
constexpr size_t CTX_OFF  = 41943040;                // ctx bf16      [4096][1024]

DEV unsigned short f2bf(float f) {
  __hip_bfloat16 h = __float2bfloat16(f);
  return __builtin_bit_cast(unsigned short, h);
}

DEV void gl_lds16(const void* g, void* l) {
  __builtin_amdgcn_global_load_lds(
      (const __attribute__((address_space(1))) void*)g,
      (__attribute__((address_space(3))) void*)l, 16, 0, 0);
}

DEV f32x4 mfma16(bf16x8 a, bf16x8 b, f32x4 c) {
  return __builtin_amdgcn_mfma_f32_16x16x32_bf16(a, b, c, 0, 0, 0);
}
DEV f32x16 mfma32(bf16x8 a, bf16x8 b, f32x16 c) {
  return __builtin_amdgcn_mfma_f32_32x32x16_bf16(a, b, c, 0, 0, 0);
}
DEV unsigned cvtpk(float lo, float hi) {
  unsigned r;
  asm("v_cvt_pk_bf16_f32 %0, %1, %2" : "=v"(r) : "v"(lo), "v"(hi));
  return r;
}
DEV float exp2_fast(float x) {   // 2^x, -inf -> 0
  float r;
  asm("v_exp_f32 %0, %1" : "=v"(r) : "v"(x));
  return r;
}
// swap a's hi 32 lanes with b's lo 32 lanes (both distinct SSA values!)
DEV void pl32(unsigned& a, unsigned& b) {
  asm("v_permlane32_swap_b32 %0, %1" : "+v"(a), "+v"(b));
}
DEV float xhalf_max(float x) {   // fmax(own, lane^32); forced-distinct copy
  float y;
  asm("v_mov_b32 %0, %1" : "=v"(y) : "v"(x));
  unsigned a = __builtin_bit_cast(unsigned, x), b = __builtin_bit_cast(unsigned, y);
  pl32(a, b);
  return fmaxf(__builtin_bit_cast(float, a), __builtin_bit_cast(float, b));
}
DEV float xhalf_add(float x) {
  float y;
  asm("v_mov_b32 %0, %1" : "=v"(y) : "v"(x));
  unsigned a = __builtin_bit_cast(unsigned, x), b = __builtin_bit_cast(unsigned, y);
  pl32(a, b);
  return __builtin_bit_cast(float, a) + __builtin_bit_cast(float, b);
}

// ---------------- f32 -> bf16 conversion, 8 elems/thread ----------------
__global__ void cvt_k(const float* __restrict__ s, unsigned short* __restrict__ d, int n8) {
  int i = blockIdx.x * 256 + threadIdx.x;
  if (i >= n8) return;
  const float4* s4 = (const float4*)s;
  float4 a = s4[2 * i], b = s4[2 * i + 1];
  u16x8 o;
  o[0] = f2bf(a.x); o[1] = f2bf(a.y); o[2] = f2bf(a.z); o[3] = f2bf(a.w);
  o[4] = f2bf(b.x); o[5] = f2bf(b.y); o[6] = f2bf(b.z); o[7] = f2bf(b.w);
  ((u16x8*)d)[i] = o;
}

// ---------------- GEMM C = A(MxK) * Bt(NxK)^T, 128x128 tile, BK=32 ----------------
template <int EPI>
__global__ __launch_bounds__(256)
void gemm_bt_k(const unsigned short* __restrict__ A,
               const unsigned short* __restrict__ Bt,
               const float* __restrict__ bias,
               unsigned short* __restrict__ qb,
               unsigned short* __restrict__ kb,
               unsigned short* __restrict__ vt,
               float* __restrict__ outf) {
  __shared__ unsigned short As[128 * 32];
  __shared__ unsigned short Bs[128 * 32];
  const int t = threadIdx.x;
  const int w = t >> 6, l = t & 63;
  const int lr = l & 15, lg = l >> 4, lk = lg * 8;
  const int m0 = blockIdx.y * 128, n0 = blockIdx.x * 128;
  const int wm = (w >> 1) * 64, wn = (w & 1) * 64;

  f32x4 acc[4][4] = {};

  const int srow = t >> 2;
  const int scolb = (t & 3) << 4;
  const char* Ag = (const char*)A + (size_t)(m0 + srow) * (KD * 2) + scolb;
  const char* Bg = (const char*)Bt + (size_t)(n0 + srow) * (KD * 2) + scolb;
  char* AsB = (char*)As;
  char* BsB = (char*)Bs;

  for (int kt = 0; kt < KD / 32; ++kt) {
    const char* ak = Ag + kt * 64;
    const char* bk = Bg + kt * 64;
    gl_lds16(ak,                 AsB + t * 16);
    gl_lds16(ak + 64 * (KD * 2), AsB + 4096 + t * 16);
    gl_lds16(bk,                 BsB + t * 16);
    gl_lds16(bk + 64 * (KD * 2), BsB + 4096 + t * 16);
    __syncthreads();

    bf16x8 a[4], b[4];
#pragma unroll
    for (int mi = 0; mi < 4; ++mi)
      a[mi] = *(const bf16x8*)&As[(wm + mi * 16 + lr) * 32 + lk];
#pragma unroll
    for (int ni = 0; ni < 4; ++ni)
      b[ni] = *(const bf16x8*)&Bs[(wn + ni * 16 + lr) * 32 + lk];
#pragma unroll
    for (int mi = 0; mi < 4; ++mi)
#pragma unroll
      for (int ni = 0; ni < 4; ++ni)
        acc[mi][ni] = mfma16(a[mi], b[ni], acc[mi][ni]);
    __syncthreads();
  }

  const int r0 = lg * 4;
  if (EPI == 0) {
    const int which = n0 >> 10;
    // K pre-scale folds softmax 1/sqrt(64) AND log2(e) (exp done as exp2)
    const float kscale = 0.125f * 1.44269504088896f;
#pragma unroll
    for (int mi = 0; mi < 4; ++mi) {
      const int sbase = m0 + wm + mi * 16 + r0;
#pragma unroll
      for (int ni = 0; ni < 4; ++ni) {
        const int e = n0 + wn + ni * 16 + lr;
        const float bv = bias[e];
        const int h = (e & 1023) >> 6, dd = e & 63;
#pragma unroll
        for (int r = 0; r < 4; ++r) {
          const float v = acc[mi][ni][r] + bv;
          const int sr = sbase + r;
          if (which == 0)      qb[((size_t)(h * S_ + sr)) * 64 + dd] = f2bf(v);
          else if (which == 1) kb[((size_t)(h * S_ + sr)) * 64 + dd] = f2bf(v * kscale);
          else                 vt[((size_t)(h * 64 + dd)) * S_ + sr] = f2bf(v);
        }
      }
    }
  } else {
#pragma unroll
    for (int mi = 0; mi < 4; ++mi) {
      const int sbase = m0 + wm + mi * 16 + r0;
#pragma unroll
      for (int ni = 0; ni < 4; ++ni) {
        const int e = n0 + wn + ni * 16 + lr;
        const float bv = bias[e];
#pragma unroll
        for (int r = 0; r < 4; ++r)
          outf[(size_t)(sbase + r) * D_ + e] = acc[mi][ni][r] + bv;
      }
    }
  }
}

// ---------------- causal flash attention, swapped-QK^T 32x32 ----------------
// grid (32 qtiles, 16 heads), 4 waves, wave owns 32 q-rows. KVBLK=64 staged
// (two 32-kv sub-tiles per barrier). S^T = K*Q^T so each lane owns one q-row:
// in-lane softmax (base-2 domain); cross-half via v_permlane32_swap_b32;
// P->PV frags via cvt_pk + permlane; T13 defer-rescale skips cacc rescale.
__global__ __launch_bounds__(256, 4)
void attn_k(const unsigned short* __restrict__ Qb,
            const unsigned short* __restrict__ Kb,
            const unsigned short* __restrict__ Vt,
            unsigned short* __restrict__ ctx) {
  __shared__ unsigned short Ks[2][64 * 64];   // [kv][d] swizzled
  __shared__ unsigned short Vs[2][64 * 64];   // [d][kv] swizzled (from V^T)

  const int t = threadIdx.x, w = t >> 6, l = t & 63;
  const int lq = l & 31, hi = l >> 5;
  const int bi = (gridDim.x - 1) - blockIdx.x;   // heavy blocks first
  const int h = blockIdx.y;
  const int q0 = bi * 128;
  const int qrow = q0 + w * 32 + lq;
  const int qwmin = q0 + w * 32, qwmax = qwmin + 31;

  const int srow = t >> 3;
  const int ssw  = ((t & 7) << 4) ^ ((srow & 7) << 4);
  const char* Kg0 = (const char*)Kb + (size_t)(h * S_) * 128;
  const char* Vg0 = (const char*)Vt + (size_t)(h * 64) * (size_t)(S_ * 2);

  // Q fragments: B-operand of S^T mfma: lane holds Q[q=lq][d0*16 + hi*8 + e]
  const unsigned short* Qr = Qb + ((size_t)(h * S_ + qrow)) * 64;
  bf16x8 qf[4];
#pragma unroll
  for (int d0 = 0; d0 < 4; ++d0)
    qf[d0] = *(const bf16x8*)(Qr + d0 * 16 + hi * 8);

  f32x16 cacc[2] = {};      // ctx^T[d][q], d-blocks 0..31 / 32..63
  float m = -INFINITY, lsum = 0.f;

  auto stage = [&](int b, int kv0) {
    char* kd = (char*)&Ks[b][0];
    const char* Kg = Kg0 + (size_t)kv0 * 128;
    gl_lds16(Kg + (size_t)srow * 128 + ssw,        kd + t * 16);
    gl_lds16(Kg + (size_t)(32 + srow) * 128 + ssw, kd + 4096 + t * 16);
    char* vd = (char*)&Vs[b][0];
    const char* Vg = Vg0 + (size_t)kv0 * 2;
    gl_lds16(Vg + (size_t)srow * (S_ * 2) + ssw,        vd + t * 16);
    gl_lds16(Vg + (size_t)(32 + srow) * (S_ * 2) + ssw, vd + 4096 + t * 16);
  };

  const int nt = 2 * (bi + 1);
  int cur = 0;
  stage(0, 0);

  for (int tt = 0; tt < nt; ++tt) {
    __syncthreads();
    if (tt + 1 < nt) stage(cur ^ 1, (tt + 1) * 64);
    const char* Kt = (const char*)&Ks[cur][0];
    const char* Vl = (const char*)&Vs[cur][0];

#pragma unroll
    for (int kvh = 0; kvh < 2; ++kvh) {
      const int kv0s = tt * 64 + kvh * 32;
      if (kv0s > qwmax) continue;     // wave-uniform: fully masked sub-tile

      // ---- S^T = K * Q^T : lane holds S^T[kv(r,hi)][q=lq] ----
      f32x16 st = {};
      const int kr = kvh * 32 + lq;
      const char* kbase = Kt + kr * 128;
      const int ksw = (kr & 7) << 4;
#pragma unroll
      for (int d0 = 0; d0 < 4; ++d0) {
        bf16x8 kf = *(const bf16x8*)(kbase + ((d0 * 32 + hi * 16) ^ ksw));
        st = mfma32(kf, qf[d0], st);
      }

      // ---- causal mask (diag-straddling sub-tiles only) ----
      if (kv0s + 31 > qwmin) {
#pragma unroll
        for (int r = 0; r < 16; ++r) {
          const int kvg = kv0s + (r & 3) + 8 * (r >> 2) + 4 * hi;
          if (kvg > qrow) st[r] = -INFINITY;
        }
      }

      // ---- in-lane online softmax, base-2 domain (lane owns q-row) ----
      float pmax = st[0];
#pragma unroll
      for (int r = 1; r < 16; ++r) pmax = fmaxf(pmax, st[r]);
      pmax = xhalf_max(pmax);

      if (!__all(pmax <= m)) {        // T13: rescale only on new max
        const float mnew = fmaxf(m, pmax);
        const float alpha = exp2_fast(m - mnew);
        lsum *= alpha;
#pragma unroll
        for (int j = 0; j < 16; ++j) { cacc[0][j] *= alpha; cacc[1][j] *= alpha; }
        m = mnew;
      }

      float p[16];
      float rs = 0.f;
#pragma unroll
      for (int r = 0; r < 16; ++r) { p[r] = exp2_fast(st[r] - m); rs += p[r]; }
      lsum += xhalf_add(rs);

      // ---- P^T B-frags: cvt_pk pairs + permlane32_swap (T12) ----
      // lane owns P^T[kv=(r&3)+8*(r>>2)+4*hi][q=lq]; B-frag needs kv=hi*8+e.
      unsigned x0 = cvtpk(p[0], p[1]),  x1 = cvtpk(p[2], p[3]);
      unsigned y0 = cvtpk(p[4], p[5]),  y1 = cvtpk(p[6], p[7]);
      pl32(x0, y0); pl32(x1, y1);
      u32x4 f0 = {x0, x1, y0, y1};
      bf16x8 pf0 = __builtin_bit_cast(bf16x8, f0);
      unsigned x2 = cvtpk(p[8], p[9]),   x3 = cvtpk(p[10], p[11]);
      unsigned y2 = cvtpk(p[12], p[13]), y3 = cvtpk(p[14], p[15]);
      pl32(x2, y2); pl32(x3, y3);
      u32x4 f1 = {x2, x3, y2, y3};
      bf16x8 pf1 = __builtin_bit_cast(bf16x8, f1);

      // ---- PV: ctx^T[d][q] += V^T * P^T ----
#pragma unroll
      for (int db = 0; db < 2; ++db) {
        const int dr = db * 32 + lq;
        const char* vbase = Vl + dr * 128;
        const int vsw = (dr & 7) << 4;
        bf16x8 v0 = *(const bf16x8*)(vbase + ((kvh * 64 + hi * 16) ^ vsw));
        bf16x8 v1 = *(const bf16x8*)(vbase + ((kvh * 64 + 32 + hi * 16) ^ vsw));
        cacc[db] = mfma32(v0, pf0, cacc[db]);
        cacc[db] = mfma32(v1, pf1, cacc[db]);
      }
    }
    cur ^= 1;
  }

  // ---- epilogue: ctx[q][h*64+d], d = (r&3)+8*(r>>2)+4*hi+32*db ----
  const float inv = 1.0f / lsum;
  unsigned short* base = ctx + (size_t)qrow * D_ + h * 64;
#pragma unroll
  for (int db = 0; db < 2; ++db)
#pragma unroll
    for (int r = 0; r < 16; r += 2) {
      const unsigned wv = cvtpk(cacc[db][r] * inv, cacc[db][r + 1] * inv);
      const int d = (r & 3) + 8 * (r >> 2) + 4 * hi + 32 * db;
      *(unsigned*)(base + d) = wv;
    }
}

extern "C" void kernel_launch(void* const* d_in, const int* in_sizes, int n_in,
                              void* d_out, int out_size, void* d_ws, size_t ws_size,
                              hipStream_t stream) {
  const float* x      = (const float*)d_in[0];
  const float* Wqkv_w = (const float*)d_in[1];
  const float* Wqkv_b = (const float*)d_in[2];
  const float* out_w  = (const float*)d_in[3];
  const float* out_b  = (const float*)d_in[4];
  float* out = (float*)d_out;
  char* ws = (char*)d_ws;

  unsigned short* xb    = (unsigned short*)(ws + XB_OFF);
  unsigned short* wqkvb = (unsigned short*)(ws + WQKV_OFF);
  unsigned short* woutb = (unsigned short*)(ws + WOUT_OFF);
  unsigned short* Qb    = (unsigned short*)(ws + QB_OFF);
  unsigned short* Kb    = (unsigned short*)(ws + KB_OFF);
  unsigned short* Vt    = (unsigned short*)(ws + VT_OFF);
  unsigned short* ctx   = (unsigned short*)(ws + CTX_OFF);

  cvt_k<<<2048, 256, 0, stream>>>(x, xb, 4096 * 1024 / 8);
  cvt_k<<<1536, 256, 0, stream>>>(Wqkv_w, wqkvb, 3072 * 1024 / 8);
  cvt_k<<<512, 256, 0, stream>>>(out_w, woutb, 1024 * 1024 / 8);

  gemm_bt_k<0><<<dim3(24, 32), 256, 0, stream>>>(xb, wqkvb, Wqkv_b, Qb, Kb, Vt, nullptr);

  attn_k<<<dim3(32, 16), 256, 0, stream>>>(Qb, Kb, Vt, ctx);

  gemm_bt_k<1><<<dim3(8, 32), 256, 0, stream>>>(ctx, woutb, out_b, nullptr, nullptr, nullptr, out);
}

// Round 7
// 168.347 us; speedup vs baseline: 1.9714x; 1.0913x over previous
//
#include <hip/hip_runtime.h>
#include <hip/hip_bf16.h>

using f32x4  = __attribute__((ext_vector_type(4))) float;
using f32x16 = __attribute__((ext_vector_type(16))) float;
using bf16x8 = __attribute__((ext_vector_type(8))) __bf16;
using u16x8  = __attribute__((ext_vector_type(8))) unsigned short;
using u32x4  = __attribute__((ext_vector_type(4))) unsigned int;

#define DEV __device__ __forceinline__

constexpr int S_  = 4096;
constexpr int D_  = 1024;
constexpr int KD  = 1024;   // contraction dim for both GEMMs

// ---- ws layout (byte offsets) ----
constexpr size_t XB_OFF   = 0;                       // x bf16        [4096][1024]
constexpr size_t WQKV_OFF = 8388608;                 // Wqkv bf16     [3072][1024]
constexpr size_t WOUT_OFF = 14680064;                // out_w bf16    [1024][1024]
constexpr size_t QB_OFF   = 16777216;                // Q bf16        [16][4096][64]
constexpr size_t KB_OFF   = 25165824;                // K*scale bf16  [16][4096][64]
constexpr size_t VT_OFF   = 33554432;                // V^T bf16      [16][64][4096]
constexpr size_t CTX_OFF  = 41943040;                // ctx bf16      [4096][1024]

DEV unsigned short f2bf(float f) {
  __hip_bfloat16 h = __float2bfloat16(f);
  return __builtin_bit_cast(unsigned short, h);
}

DEV void gl_lds16(const void* g, void* l) {
  __builtin_amdgcn_global_load_lds(
      (const __attribute__((address_space(1))) void*)g,
      (__attribute__((address_space(3))) void*)l, 16, 0, 0);
}

DEV f32x4 mfma16(bf16x8 a, bf16x8 b, f32x4 c) {
  return __builtin_amdgcn_mfma_f32_16x16x32_bf16(a, b, c, 0, 0, 0);
}
DEV f32x16 mfma32(bf16x8 a, bf16x8 b, f32x16 c) {
  return __builtin_amdgcn_mfma_f32_32x32x16_bf16(a, b, c, 0, 0, 0);
}
DEV unsigned cvtpk(float lo, float hi) {
  unsigned r;
  asm("v_cvt_pk_bf16_f32 %0, %1, %2" : "=v"(r) : "v"(lo), "v"(hi));
  return r;
}
DEV float exp2_fast(float x) {   // 2^x, -inf -> 0
  float r;
  asm("v_exp_f32 %0, %1" : "=v"(r) : "v"(x));
  return r;
}
// swap a's hi 32 lanes with b's lo 32 lanes (both distinct SSA values!)
DEV void pl32(unsigned& a, unsigned& b) {
  asm("v_permlane32_swap_b32 %0, %1" : "+v"(a), "+v"(b));
}
DEV float xhalf_max(float x) {   // fmax(own, lane^32); forced-distinct copy
  float y;
  asm("v_mov_b32 %0, %1" : "=v"(y) : "v"(x));
  unsigned a = __builtin_bit_cast(unsigned, x), b = __builtin_bit_cast(unsigned, y);
  pl32(a, b);
  return fmaxf(__builtin_bit_cast(float, a), __builtin_bit_cast(float, b));
}
DEV float xhalf_add(float x) {
  float y;
  asm("v_mov_b32 %0, %1" : "=v"(y) : "v"(x));
  unsigned a = __builtin_bit_cast(unsigned, x), b = __builtin_bit_cast(unsigned, y);
  pl32(a, b);
  return __builtin_bit_cast(float, a) + __builtin_bit_cast(float, b);
}

// ---------------- f32 -> bf16 conversion, 8 elems/thread ----------------
__global__ void cvt_k(const float* __restrict__ s, unsigned short* __restrict__ d, int n8) {
  int i = blockIdx.x * 256 + threadIdx.x;
  if (i >= n8) return;
  const float4* s4 = (const float4*)s;
  float4 a = s4[2 * i], b = s4[2 * i + 1];
  u16x8 o;
  o[0] = f2bf(a.x); o[1] = f2bf(a.y); o[2] = f2bf(a.z); o[3] = f2bf(a.w);
  o[4] = f2bf(b.x); o[5] = f2bf(b.y); o[6] = f2bf(b.z); o[7] = f2bf(b.w);
  ((u16x8*)d)[i] = o;
}

// ---------------- GEMM C = A(MxK) * Bt(NxK)^T, 128x128 tile, BK=32 ----------------
template <int EPI>
__global__ __launch_bounds__(256)
void gemm_bt_k(const unsigned short* __restrict__ A,
               const unsigned short* __restrict__ Bt,
               const float* __restrict__ bias,
               unsigned short* __restrict__ qb,
               unsigned short* __restrict__ kb,
               unsigned short* __restrict__ vt,
               float* __restrict__ outf) {
  __shared__ unsigned short As[128 * 32];
  __shared__ unsigned short Bs[128 * 32];
  const int t = threadIdx.x;
  const int w = t >> 6, l = t & 63;
  const int lr = l & 15, lg = l >> 4, lk = lg * 8;
  const int m0 = blockIdx.y * 128, n0 = blockIdx.x * 128;
  const int wm = (w >> 1) * 64, wn = (w & 1) * 64;

  f32x4 acc[4][4] = {};

  const int srow = t >> 2;
  const int scolb = (t & 3) << 4;
  const char* Ag = (const char*)A + (size_t)(m0 + srow) * (KD * 2) + scolb;
  const char* Bg = (const char*)Bt + (size_t)(n0 + srow) * (KD * 2) + scolb;
  char* AsB = (char*)As;
  char* BsB = (char*)Bs;

  for (int kt = 0; kt < KD / 32; ++kt) {
    const char* ak = Ag + kt * 64;
    const char* bk = Bg + kt * 64;
    gl_lds16(ak,                 AsB + t * 16);
    gl_lds16(ak + 64 * (KD * 2), AsB + 4096 + t * 16);
    gl_lds16(bk,                 BsB + t * 16);
    gl_lds16(bk + 64 * (KD * 2), BsB + 4096 + t * 16);
    __syncthreads();

    bf16x8 a[4], b[4];
#pragma unroll
    for (int mi = 0; mi < 4; ++mi)
      a[mi] = *(const bf16x8*)&As[(wm + mi * 16 + lr) * 32 + lk];
#pragma unroll
    for (int ni = 0; ni < 4; ++ni)
      b[ni] = *(const bf16x8*)&Bs[(wn + ni * 16 + lr) * 32 + lk];
#pragma unroll
    for (int mi = 0; mi < 4; ++mi)
#pragma unroll
      for (int ni = 0; ni < 4; ++ni)
        acc[mi][ni] = mfma16(a[mi], b[ni], acc[mi][ni]);
    __syncthreads();
  }

  const int r0 = lg * 4;
  if (EPI == 0) {
    const int which = n0 >> 10;
    // K pre-scale folds softmax 1/sqrt(64) AND log2(e) (exp done as exp2)
    const float kscale = 0.125f * 1.44269504088896f;
#pragma unroll
    for (int mi = 0; mi < 4; ++mi) {
      const int sbase = m0 + wm + mi * 16 + r0;
#pragma unroll
      for (int ni = 0; ni < 4; ++ni) {
        const int e = n0 + wn + ni * 16 + lr;
        const float bv = bias[e];
        const int h = (e & 1023) >> 6, dd = e & 63;
#pragma unroll
        for (int r = 0; r < 4; ++r) {
          const float v = acc[mi][ni][r] + bv;
          const int sr = sbase + r;
          if (which == 0)      qb[((size_t)(h * S_ + sr)) * 64 + dd] = f2bf(v);
          else if (which == 1) kb[((size_t)(h * S_ + sr)) * 64 + dd] = f2bf(v * kscale);
          else                 vt[((size_t)(h * 64 + dd)) * S_ + sr] = f2bf(v);
        }
      }
    }
  } else {
#pragma unroll
    for (int mi = 0; mi < 4; ++mi) {
      const int sbase = m0 + wm + mi * 16 + r0;
#pragma unroll
      for (int ni = 0; ni < 4; ++ni) {
        const int e = n0 + wn + ni * 16 + lr;
        const float bv = bias[e];
#pragma unroll
        for (int r = 0; r < 4; ++r)
          outf[(size_t)(sbase + r) * D_ + e] = acc[mi][ni][r] + bv;
      }
    }
  }
}

// ---------------- causal flash attention, swapped-QK^T 32x32, intra-block KV split ----
// grid (32 qtiles, 16 heads), 512 thr = 8 waves. Wave-group g = w8>>2 handles
// half the kv range (g=1 gets the diagonal half) for the SAME 128 q-rows.
// Each group has its own double-buffered K/V LDS, staged by its own 256-thread
// half. Partial (m, lsum, cacc) combined through LDS at the end.
__global__ __launch_bounds__(512, 2)
void attn_k(const unsigned short* __restrict__ Qb,
            const unsigned short* __restrict__ Kb,
            const unsigned short* __restrict__ Vt,
            unsigned short* __restrict__ ctx) {
  __shared__ char smem[65536];
  // bytes [0,32768): K tiles   [g][buf][8192]
  // bytes [32768,65536): V tiles [g][buf][8192]
  // combine overlay (after final barrier): f32[4 waves][64 lanes][36]

  const int t = threadIdx.x;
  const int w8 = t >> 6;              // 0..7
  const int g  = w8 >> 2;             // kv-split group
  const int w  = w8 & 3;              // q sub-tile
  const int l = t & 63, lq = l & 31, hi = l >> 5;
  const int bi = (gridDim.x - 1) - blockIdx.x;   // heavy blocks first
  const int h = blockIdx.y;
  const int q0 = bi * 128;
  const int qrow = q0 + w * 32 + lq;
  const int qwmin = q0 + w * 32, qwmax = qwmin + 31;
  const int niter = bi + 1;           // kv tiles per group

  // staging: thread-half sg stages group sg's buffers
  const int sg = t >> 8;
  const int ts = t & 255;
  const int srow = ts >> 3;
  const int ssw  = ((ts & 7) << 4) ^ ((srow & 7) << 4);
  const char* Kg0 = (const char*)Kb + (size_t)(h * S_) * 128;
  const char* Vg0 = (const char*)Vt + (size_t)(h * 64) * (size_t)(S_ * 2);

  // Q fragments: B-operand of S^T mfma: lane holds Q[q=lq][d0*16 + hi*8 + e]
  const unsigned short* Qr = Qb + ((size_t)(h * S_ + qrow)) * 64;
  bf16x8 qf[4];
#pragma unroll
  for (int d0 = 0; d0 < 4; ++d0)
    qf[d0] = *(const bf16x8*)(Qr + d0 * 16 + hi * 8);

  f32x16 cacc[2] = {};      // ctx^T[d][q], d-blocks 0..31 / 32..63
  float m = -INFINITY, lsum = 0.f;

  auto stage = [&](int buf, int it) {
    const int kv0 = (it + sg * niter) * 64;
    char* kd = smem + sg * 16384 + buf * 8192;
    const char* Kg = Kg0 + (size_t)kv0 * 128;
    gl_lds16(Kg + (size_t)srow * 128 + ssw,        kd + ts * 16);
    gl_lds16(Kg + (size_t)(32 + srow) * 128 + ssw, kd + 4096 + ts * 16);
    char* vd = smem + 32768 + sg * 16384 + buf * 8192;
    const char* Vg = Vg0 + (size_t)kv0 * 2;
    gl_lds16(Vg + (size_t)srow * (S_ * 2) + ssw,        vd + ts * 16);
    gl_lds16(Vg + (size_t)(32 + srow) * (S_ * 2) + ssw, vd + 4096 + ts * 16);
  };

  int cur = 0;
  stage(0, 0);

  for (int it = 0; it < niter; ++it) {
    __syncthreads();
    if (it + 1 < niter) stage(cur ^ 1, it + 1);
    const char* Kt = smem + g * 16384 + cur * 8192;
    const char* Vl = smem + 32768 + g * 16384 + cur * 8192;
    const int tt = it + g * niter;

#pragma unroll
    for (int kvh = 0; kvh < 2; ++kvh) {
      const int kv0s = tt * 64 + kvh * 32;
      if (kv0s > qwmax) continue;     // wave-uniform: fully masked sub-tile

      // ---- S^T = K * Q^T : lane holds S^T[kv(r,hi)][q=lq] ----
      f32x16 st = {};
      const int kr = kvh * 32 + lq;
      const char* kbase = Kt + kr * 128;
      const int ksw = (kr & 7) << 4;
#pragma unroll
      for (int d0 = 0; d0 < 4; ++d0) {
        bf16x8 kf = *(const bf16x8*)(kbase + ((d0 * 32 + hi * 16) ^ ksw));
        st = mfma32(kf, qf[d0], st);
      }

      // ---- causal mask (diag-straddling sub-tiles only) ----
      if (kv0s + 31 > qwmin) {
#pragma unroll
        for (int r = 0; r < 16; ++r) {
          const int kvg = kv0s + (r & 3) + 8 * (r >> 2) + 4 * hi;
          if (kvg > qrow) st[r] = -INFINITY;
        }
      }

      // ---- in-lane online softmax, base-2 domain (lane owns q-row) ----
      float pmax = st[0];
#pragma unroll
      for (int r = 1; r < 16; ++r) pmax = fmaxf(pmax, st[r]);
      pmax = xhalf_max(pmax);

      if (!__all(pmax <= m)) {        // T13: rescale only on new max
        const float mnew = fmaxf(m, pmax);
        const float alpha = exp2_fast(m - mnew);
        lsum *= alpha;
#pragma unroll
        for (int j = 0; j < 16; ++j) { cacc[0][j] *= alpha; cacc[1][j] *= alpha; }
        m = mnew;
      }

      float p[16];
      float rs = 0.f;
#pragma unroll
      for (int r = 0; r < 16; ++r) { p[r] = exp2_fast(st[r] - m); rs += p[r]; }
      lsum += xhalf_add(rs);

      // ---- P^T B-frags: cvt_pk pairs + permlane32_swap (T12) ----
      unsigned x0 = cvtpk(p[0], p[1]),  x1 = cvtpk(p[2], p[3]);
      unsigned y0 = cvtpk(p[4], p[5]),  y1 = cvtpk(p[6], p[7]);
      pl32(x0, y0); pl32(x1, y1);
      u32x4 f0 = {x0, x1, y0, y1};
      bf16x8 pf0 = __builtin_bit_cast(bf16x8, f0);
      unsigned x2 = cvtpk(p[8], p[9]),   x3 = cvtpk(p[10], p[11]);
      unsigned y2 = cvtpk(p[12], p[13]), y3 = cvtpk(p[14], p[15]);
      pl32(x2, y2); pl32(x3, y3);
      u32x4 f1 = {x2, x3, y2, y3};
      bf16x8 pf1 = __builtin_bit_cast(bf16x8, f1);

      // ---- PV: ctx^T[d][q] += V^T * P^T ----
#pragma unroll
      for (int db = 0; db < 2; ++db) {
        const int dr = db * 32 + lq;
        const char* vbase = Vl + dr * 128;
        const int vsw = (dr & 7) << 4;
        bf16x8 v0 = *(const bf16x8*)(vbase + ((kvh * 64 + hi * 16) ^ vsw));
        bf16x8 v1 = *(const bf16x8*)(vbase + ((kvh * 64 + 32 + hi * 16) ^ vsw));
        cacc[db] = mfma32(v0, pf0, cacc[db]);
        cacc[db] = mfma32(v1, pf1, cacc[db]);
      }
    }
    cur ^= 1;
  }

  // ---- combine group partials through LDS ----
  __syncthreads();
  float* comb = (float*)smem;
  float* slot = comb + (size_t)(w * 64 + l) * 36;
  if (g == 1) {
    slot[0] = m; slot[1] = lsum;
#pragma unroll
    for (int j = 0; j < 16; ++j) { slot[4 + j] = cacc[0][j]; slot[20 + j] = cacc[1][j]; }
  }
  __syncthreads();
  if (g == 0) {
    const float m1 = slot[0], l1 = slot[1];
    const float M = fmaxf(m, m1);
    const float a0 = exp2_fast(m - M), a1 = exp2_fast(m1 - M);
    const float inv = 1.0f / (lsum * a0 + l1 * a1);
    const float s0 = a0 * inv, s1 = a1 * inv;
    unsigned short* base = ctx + (size_t)qrow * D_ + h * 64;
#pragma unroll
    for (int db = 0; db < 2; ++db)
#pragma unroll
      for (int r = 0; r < 16; r += 2) {
        const float o0 = cacc[db][r]     * s0 + slot[4 + db * 16 + r]     * s1;
        const float o1 = cacc[db][r + 1] * s0 + slot[4 + db * 16 + r + 1] * s1;
        const unsigned wv = cvtpk(o0, o1);
        const int d = (r & 3) + 8 * (r >> 2) + 4 * hi + 32 * db;
        *(unsigned*)(base + d) = wv;
      }
  }
}

extern "C" void kernel_launch(void* const* d_in, const int* in_sizes, int n_in,
                              void* d_out, int out_size, void* d_ws, size_t ws_size,
                              hipStream_t stream) {
  const float* x      = (const float*)d_in[0];
  const float* Wqkv_w = (const float*)d_in[1];
  const float* Wqkv_b = (const float*)d_in[2];
  const float* out_w  = (const float*)d_in[3];
  const float* out_b  = (const float*)d_in[4];
  float* out = (float*)d_out;
  char* ws = (char*)d_ws;

  unsigned short* xb    = (unsigned short*)(ws + XB_OFF);
  unsigned short* wqkvb = (unsigned short*)(ws + WQKV_OFF);
  unsigned short* woutb = (unsigned short*)(ws + WOUT_OFF);
  unsigned short* Qb    = (unsigned short*)(ws + QB_OFF);
  unsigned short* Kb    = (unsigned short*)(ws + KB_OFF);
  unsigned short* Vt    = (unsigned short*)(ws + VT_OFF);
  unsigned short* ctx   = (unsigned short*)(ws + CTX_OFF);

  cvt_k<<<2048, 256, 0, stream>>>(x, xb, 4096 * 1024 / 8);
  cvt_k<<<1536, 256, 0, stream>>>(Wqkv_w, wqkvb, 3072 * 1024 / 8);
  cvt_k<<<512, 256, 0, stream>>>(out_w, woutb, 1024 * 1024 / 8);

  gemm_bt_k<0><<<dim3(24, 32), 256, 0, stream>>>(xb, wqkvb, Wqkv_b, Qb, Kb, Vt, nullptr);

  attn_k<<<dim3(32, 16), 512, 0, stream>>>(Qb, Kb, Vt, ctx);

  gemm_bt_k<1><<<dim3(8, 32), 256, 0, stream>>>(ctx, woutb, out_b, nullptr, nullptr, nullptr, out);
}

// Round 8
// 139.178 us; speedup vs baseline: 2.3846x; 1.2096x over previous
//
#include <hip/hip_runtime.h>
#include <hip/hip_bf16.h>

using f32x4  = __attribute__((ext_vector_type(4))) float;
using f32x16 = __attribute__((ext_vector_type(16))) float;
using bf16x8 = __attribute__((ext_vector_type(8))) __bf16;
using u16x8  = __attribute__((ext_vector_type(8))) unsigned short;
using u32x4  = __attribute__((ext_vector_type(4))) unsigned int;

#define DEV __device__ __forceinline__

constexpr int S_  = 4096;
constexpr int D_  = 1024;
constexpr int KD  = 1024;   // contraction dim for both GEMMs

// ---- ws layout (byte offsets) ----
constexpr size_t XB_OFF   = 0;                       // x bf16        [4096][1024]
constexpr size_t WQKV_OFF = 8388608;                 // Wqkv bf16     [3072][1024]
constexpr size_t WOUT_OFF = 14680064;                // out_w bf16    [1024][1024]
constexpr size_t QB_OFF   = 16777216;                // Q bf16        [16][4096][64]
constexpr size_t KB_OFF   = 25165824;                // K*scale bf16  [16][4096][64]
constexpr size_t VT_OFF   = 33554432;                // V^T bf16      [16][64][4096]
constexpr size_t CTX_OFF  = 41943040;                // ctx bf16      [4096][1024]

DEV unsigned short f2bf(float f) {
  __hip_bfloat16 h = __float2bfloat16(f);
  return __builtin_bit_cast(unsigned short, h);
}

DEV void gl_lds16(const void* g, void* l) {
  __builtin_amdgcn_global_load_lds(
      (const __attribute__((address_space(1))) void*)g,
      (__attribute__((address_space(3))) void*)l, 16, 0, 0);
}

DEV f32x4 mfma16(bf16x8 a, bf16x8 b, f32x4 c) {
  return __builtin_amdgcn_mfma_f32_16x16x32_bf16(a, b, c, 0, 0, 0);
}
DEV f32x16 mfma32(bf16x8 a, bf16x8 b, f32x16 c) {
  return __builtin_amdgcn_mfma_f32_32x32x16_bf16(a, b, c, 0, 0, 0);
}
DEV unsigned cvtpk(float lo, float hi) {
  unsigned r;
  asm("v_cvt_pk_bf16_f32 %0, %1, %2" : "=v"(r) : "v"(lo), "v"(hi));
  return r;
}
DEV float exp2_fast(float x) {   // 2^x, -inf -> 0
  float r;
  asm("v_exp_f32 %0, %1" : "=v"(r) : "v"(x));
  return r;
}
// swap a's hi 32 lanes with b's lo 32 lanes (both distinct SSA values!)
DEV void pl32(unsigned& a, unsigned& b) {
  asm("v_permlane32_swap_b32 %0, %1" : "+v"(a), "+v"(b));
}
DEV float xhalf_max(float x) {   // fmax(own, lane^32); forced-distinct copy
  float y;
  asm("v_mov_b32 %0, %1" : "=v"(y) : "v"(x));
  unsigned a = __builtin_bit_cast(unsigned, x), b = __builtin_bit_cast(unsigned, y);
  pl32(a, b);
  return fmaxf(__builtin_bit_cast(float, a), __builtin_bit_cast(float, b));
}
DEV float xhalf_add(float x) {
  float y;
  asm("v_mov_b32 %0, %1" : "=v"(y) : "v"(x));
  unsigned a = __builtin_bit_cast(unsigned, x), b = __builtin_bit_cast(unsigned, y);
  pl32(a, b);
  return __builtin_bit_cast(float, a) + __builtin_bit_cast(float, b);
}

// ---------------- f32 -> bf16 conversion, 8 elems/thread ----------------
__global__ void cvt_k(const float* __restrict__ s, unsigned short* __restrict__ d, int n8) {
  int i = blockIdx.x * 256 + threadIdx.x;
  if (i >= n8) return;
  const float4* s4 = (const float4*)s;
  float4 a = s4[2 * i], b = s4[2 * i + 1];
  u16x8 o;
  o[0] = f2bf(a.x); o[1] = f2bf(a.y); o[2] = f2bf(a.z); o[3] = f2bf(a.w);
  o[4] = f2bf(b.x); o[5] = f2bf(b.y); o[6] = f2bf(b.z); o[7] = f2bf(b.w);
  ((u16x8*)d)[i] = o;
}

// ---------------- GEMM C = A(MxK) * Bt(NxK)^T, 128x128 tile, BK=32 ----------------
template <int EPI>
__global__ __launch_bounds__(256)
void gemm_bt_k(const unsigned short* __restrict__ A,
               const unsigned short* __restrict__ Bt,
               const float* __restrict__ bias,
               unsigned short* __restrict__ qb,
               unsigned short* __restrict__ kb,
               unsigned short* __restrict__ vt,
               float* __restrict__ outf) {
  __shared__ unsigned short As[128 * 32];
  __shared__ unsigned short Bs[128 * 32];
  const int t = threadIdx.x;
  const int w = t >> 6, l = t & 63;
  const int lr = l & 15, lg = l >> 4, lk = lg * 8;
  const int m0 = blockIdx.y * 128, n0 = blockIdx.x * 128;
  const int wm = (w >> 1) * 64, wn = (w & 1) * 64;

  f32x4 acc[4][4] = {};

  const int srow = t >> 2;
  const int scolb = (t & 3) << 4;
  const char* Ag = (const char*)A + (size_t)(m0 + srow) * (KD * 2) + scolb;
  const char* Bg = (const char*)Bt + (size_t)(n0 + srow) * (KD * 2) + scolb;
  char* AsB = (char*)As;
  char* BsB = (char*)Bs;

  for (int kt = 0; kt < KD / 32; ++kt) {
    const char* ak = Ag + kt * 64;
    const char* bk = Bg + kt * 64;
    gl_lds16(ak,                 AsB + t * 16);
    gl_lds16(ak + 64 * (KD * 2), AsB + 4096 + t * 16);
    gl_lds16(bk,                 BsB + t * 16);
    gl_lds16(bk + 64 * (KD * 2), BsB + 4096 + t * 16);
    __syncthreads();

    bf16x8 a[4], b[4];
#pragma unroll
    for (int mi = 0; mi < 4; ++mi)
      a[mi] = *(const bf16x8*)&As[(wm + mi * 16 + lr) * 32 + lk];
#pragma unroll
    for (int ni = 0; ni < 4; ++ni)
      b[ni] = *(const bf16x8*)&Bs[(wn + ni * 16 + lr) * 32 + lk];
#pragma unroll
    for (int mi = 0; mi < 4; ++mi)
#pragma unroll
      for (int ni = 0; ni < 4; ++ni)
        acc[mi][ni] = mfma16(a[mi], b[ni], acc[mi][ni]);
    __syncthreads();
  }

  const int r0 = lg * 4;
  if (EPI == 0) {
    const int which = n0 >> 10;
    // K pre-scale folds softmax 1/sqrt(64) AND log2(e) (exp done as exp2)
    const float kscale = 0.125f * 1.44269504088896f;
#pragma unroll
    for (int mi = 0; mi < 4; ++mi) {
      const int sbase = m0 + wm + mi * 16 + r0;
#pragma unroll
      for (int ni = 0; ni < 4; ++ni) {
        const int e = n0 + wn + ni * 16 + lr;
        const float bv = bias[e];
        const int h = (e & 1023) >> 6, dd = e & 63;
#pragma unroll
        for (int r = 0; r < 4; ++r) {
          const float v = acc[mi][ni][r] + bv;
          const int sr = sbase + r;
          if (which == 0)      qb[((size_t)(h * S_ + sr)) * 64 + dd] = f2bf(v);
          else if (which == 1) kb[((size_t)(h * S_ + sr)) * 64 + dd] = f2bf(v * kscale);
          else                 vt[((size_t)(h * 64 + dd)) * S_ + sr] = f2bf(v);
        }
      }
    }
  } else {
#pragma unroll
    for (int mi = 0; mi < 4; ++mi) {
      const int sbase = m0 + wm + mi * 16 + r0;
#pragma unroll
      for (int ni = 0; ni < 4; ++ni) {
        const int e = n0 + wn + ni * 16 + lr;
        const float bv = bias[e];
#pragma unroll
        for (int r = 0; r < 4; ++r)
          outf[(size_t)(sbase + r) * D_ + e] = acc[mi][ni][r] + bv;
      }
    }
  }
}

// ---------------- causal flash attention, swapped-QK^T 32x32 ----------------
// Balanced pairing: grid (16 pairs, 16 heads), 512 thr = 8 waves. Each block
// processes TWO q-tiles: bi = 31-pairIdx (heavy) then bi = pairIdx (light);
// total kv-tile iters = 33 for every block -> uniform CU load.
// Within a task: wave-group g = w8>>2 handles half the kv range (kv split),
// own double-buffered K/V LDS; partials combined through LDS at task end.
__global__ __launch_bounds__(512, 2)
void attn_k(const unsigned short* __restrict__ Qb,
            const unsigned short* __restrict__ Kb,
            const unsigned short* __restrict__ Vt,
            unsigned short* __restrict__ ctx) {
  __shared__ char smem[65536];
  // bytes [0,32768): K tiles   [g][buf][8192]
  // bytes [32768,65536): V tiles [g][buf][8192]
  // combine overlay (after post-loop barrier): f32[4 waves][64 lanes][36]

  const int t = threadIdx.x;
  const int w8 = t >> 6;              // 0..7
  const int g  = w8 >> 2;             // kv-split group
  const int w  = w8 & 3;              // q sub-tile
  const int l = t & 63, lq = l & 31, hi = l >> 5;
  const int pairIdx = blockIdx.x;     // 0..15
  const int h = blockIdx.y;

  // staging: thread-half sg stages group sg's buffers
  const int sg = t >> 8;
  const int ts = t & 255;
  const int srow = ts >> 3;
  const int ssw  = ((ts & 7) << 4) ^ ((srow & 7) << 4);
  const char* Kg0 = (const char*)Kb + (size_t)(h * S_) * 128;
  const char* Vg0 = (const char*)Vt + (size_t)(h * 64) * (size_t)(S_ * 2);

  for (int task = 0; task < 2; ++task) {
    const int bi = task == 0 ? (31 - pairIdx) : pairIdx;
    const int q0 = bi * 128;
    const int qrow = q0 + w * 32 + lq;
    const int qwmin = q0 + w * 32, qwmax = qwmin + 31;
    const int niter = bi + 1;         // kv tiles per group

    // Q fragments: B-operand of S^T mfma: lane holds Q[q=lq][d0*16 + hi*8 + e]
    const unsigned short* Qr = Qb + ((size_t)(h * S_ + qrow)) * 64;
    bf16x8 qf[4];
#pragma unroll
    for (int d0 = 0; d0 < 4; ++d0)
      qf[d0] = *(const bf16x8*)(Qr + d0 * 16 + hi * 8);

    f32x16 cacc[2] = {};      // ctx^T[d][q], d-blocks 0..31 / 32..63
    float m = -INFINITY, lsum = 0.f;

    auto stage = [&](int buf, int it) {
      const int kv0 = (it + sg * niter) * 64;
      char* kd = smem + sg * 16384 + buf * 8192;
      const char* Kg = Kg0 + (size_t)kv0 * 128;
      gl_lds16(Kg + (size_t)srow * 128 + ssw,        kd + ts * 16);
      gl_lds16(Kg + (size_t)(32 + srow) * 128 + ssw, kd + 4096 + ts * 16);
      char* vd = smem + 32768 + sg * 16384 + buf * 8192;
      const char* Vg = Vg0 + (size_t)kv0 * 2;
      gl_lds16(Vg + (size_t)srow * (S_ * 2) + ssw,        vd + ts * 16);
      gl_lds16(Vg + (size_t)(32 + srow) * (S_ * 2) + ssw, vd + 4096 + ts * 16);
    };

    int cur = 0;
    stage(0, 0);

    for (int it = 0; it < niter; ++it) {
      __syncthreads();
      if (it + 1 < niter) stage(cur ^ 1, it + 1);
      const char* Kt = smem + g * 16384 + cur * 8192;
      const char* Vl = smem + 32768 + g * 16384 + cur * 8192;
      const int tt = it + g * niter;

#pragma unroll
      for (int kvh = 0; kvh < 2; ++kvh) {
        const int kv0s = tt * 64 + kvh * 32;
        if (kv0s > qwmax) continue;   // wave-uniform: fully masked sub-tile

        // ---- S^T = K * Q^T : lane holds S^T[kv(r,hi)][q=lq] ----
        f32x16 st = {};
        const int kr = kvh * 32 + lq;
        const char* kbase = Kt + kr * 128;
        const int ksw = (kr & 7) << 4;
#pragma unroll
        for (int d0 = 0; d0 < 4; ++d0) {
          bf16x8 kf = *(const bf16x8*)(kbase + ((d0 * 32 + hi * 16) ^ ksw));
          st = mfma32(kf, qf[d0], st);
        }

        // ---- causal mask (diag-straddling sub-tiles only) ----
        if (kv0s + 31 > qwmin) {
#pragma unroll
          for (int r = 0; r < 16; ++r) {
            const int kvg = kv0s + (r & 3) + 8 * (r >> 2) + 4 * hi;
            if (kvg > qrow) st[r] = -INFINITY;
          }
        }

        // ---- in-lane online softmax, base-2 domain (lane owns q-row) ----
        float pmax = st[0];
#pragma unroll
        for (int r = 1; r < 16; ++r) pmax = fmaxf(pmax, st[r]);
        pmax = xhalf_max(pmax);

        if (!__all(pmax <= m)) {      // T13: rescale only on new max
          const float mnew = fmaxf(m, pmax);
          const float alpha = exp2_fast(m - mnew);
          lsum *= alpha;
#pragma unroll
          for (int j = 0; j < 16; ++j) { cacc[0][j] *= alpha; cacc[1][j] *= alpha; }
          m = mnew;
        }

        float p[16];
        float rs = 0.f;
#pragma unroll
        for (int r = 0; r < 16; ++r) { p[r] = exp2_fast(st[r] - m); rs += p[r]; }
        lsum += xhalf_add(rs);

        // ---- P^T B-frags: cvt_pk pairs + permlane32_swap (T12) ----
        unsigned x0 = cvtpk(p[0], p[1]),  x1 = cvtpk(p[2], p[3]);
        unsigned y0 = cvtpk(p[4], p[5]),  y1 = cvtpk(p[6], p[7]);
        pl32(x0, y0); pl32(x1, y1);
        u32x4 f0 = {x0, x1, y0, y1};
        bf16x8 pf0 = __builtin_bit_cast(bf16x8, f0);
        unsigned x2 = cvtpk(p[8], p[9]),   x3 = cvtpk(p[10], p[11]);
        unsigned y2 = cvtpk(p[12], p[13]), y3 = cvtpk(p[14], p[15]);
        pl32(x2, y2); pl32(x3, y3);
        u32x4 f1 = {x2, x3, y2, y3};
        bf16x8 pf1 = __builtin_bit_cast(bf16x8, f1);

        // ---- PV: ctx^T[d][q] += V^T * P^T ----
#pragma unroll
        for (int db = 0; db < 2; ++db) {
          const int dr = db * 32 + lq;
          const char* vbase = Vl + dr * 128;
          const int vsw = (dr & 7) << 4;
          bf16x8 v0 = *(const bf16x8*)(vbase + ((kvh * 64 + hi * 16) ^ vsw));
          bf16x8 v1 = *(const bf16x8*)(vbase + ((kvh * 64 + 32 + hi * 16) ^ vsw));
          cacc[db] = mfma32(v0, pf0, cacc[db]);
          cacc[db] = mfma32(v1, pf1, cacc[db]);
        }
      }
      cur ^= 1;
    }

    // ---- combine group partials through LDS ----
    __syncthreads();                  // all staged loads drained; overlay safe
    float* comb = (float*)smem;
    float* slot = comb + (size_t)(w * 64 + l) * 36;
    if (g == 1) {
      slot[0] = m; slot[1] = lsum;
#pragma unroll
      for (int j = 0; j < 16; ++j) { slot[4 + j] = cacc[0][j]; slot[20 + j] = cacc[1][j]; }
    }
    __syncthreads();
    if (g == 0) {
      const float m1 = slot[0], l1 = slot[1];
      const float M = fmaxf(m, m1);
      const float a0 = exp2_fast(m - M), a1 = exp2_fast(m1 - M);
      const float inv = 1.0f / (lsum * a0 + l1 * a1);
      const float s0 = a0 * inv, s1 = a1 * inv;
      unsigned short* base = ctx + (size_t)qrow * D_ + h * 64;
#pragma unroll
      for (int db = 0; db < 2; ++db)
#pragma unroll
        for (int r = 0; r < 16; r += 2) {
          const float o0 = cacc[db][r]     * s0 + slot[4 + db * 16 + r]     * s1;
          const float o1 = cacc[db][r + 1] * s0 + slot[4 + db * 16 + r + 1] * s1;
          const unsigned wv = cvtpk(o0, o1);
          const int d = (r & 3) + 8 * (r >> 2) + 4 * hi + 32 * db;
          *(unsigned*)(base + d) = wv;
        }
    }
    __syncthreads();                  // protect overlay until g0 done reading
  }
}

extern "C" void kernel_launch(void* const* d_in, const int* in_sizes, int n_in,
                              void* d_out, int out_size, void* d_ws, size_t ws_size,
                              hipStream_t stream) {
  const float* x      = (const float*)d_in[0];
  const float* Wqkv_w = (const float*)d_in[1];
  const float* Wqkv_b = (const float*)d_in[2];
  const float* out_w  = (const float*)d_in[3];
  const float* out_b  = (const float*)d_in[4];
  float* out = (float*)d_out;
  char* ws = (char*)d_ws;

  unsigned short* xb    = (unsigned short*)(ws + XB_OFF);
  unsigned short* wqkvb = (unsigned short*)(ws + WQKV_OFF);
  unsigned short* woutb = (unsigned short*)(ws + WOUT_OFF);
  unsigned short* Qb    = (unsigned short*)(ws + QB_OFF);
  unsigned short* Kb    = (unsigned short*)(ws + KB_OFF);
  unsigned short* Vt    = (unsigned short*)(ws + VT_OFF);
  unsigned short* ctx   = (unsigned short*)(ws + CTX_OFF);

  cvt_k<<<2048, 256, 0, stream>>>(x, xb, 4096 * 1024 / 8);
  cvt_k<<<1536, 256, 0, stream>>>(Wqkv_w, wqkvb, 3072 * 1024 / 8);
  cvt_k<<<512, 256, 0, stream>>>(out_w, woutb, 1024 * 1024 / 8);

  gemm_bt_k<0><<<dim3(24, 32), 256, 0, stream>>>(xb, wqkvb, Wqkv_b, Qb, Kb, Vt, nullptr);

  attn_k<<<dim3(16, 16), 512, 0, stream>>>(Qb, Kb, Vt, ctx);

  gemm_bt_k<1><<<dim3(8, 32), 256, 0, stream>>>(ctx, woutb, out_b, nullptr, nullptr, nullptr, out);
}